// Round 5
// baseline (101273.181 us; speedup 1.0000x reference)
//
#include <hip/hip_runtime.h>
#include <hip/hip_bf16.h>
#include <math.h>

// ============================================================================
// RNNDecoder v7: v4/v5 structure (128 independent persistent blocks, one row
// each, zero inter-block sync in the loop) rebuilt for REGISTER HEADROOM:
// NT=512 with __launch_bounds__(512,2) -> 256 VGPR/thread. The v5/v6
// post-mortem showed VGPR_Count=64 forced scratch-spills of the GRU h-slice
// and broke all load batching into serial load->wait->use chains (~1
// outstanding miss/wave). v7: GRU = 3 full rows/thread (v4's exact per-row
// chain), h read as wave-uniform LDS broadcasts, 24 dwordx4 in flight per
// chunk; cc = both halves per thread (two independent load chains). All
// accumulation orders element-identical to the passing v4/v5 trajectory.
// ============================================================================

typedef unsigned short u16;
typedef unsigned int u32;
typedef float f4 __attribute__((ext_vector_type(4)));
typedef u32 u4 __attribute__((ext_vector_type(4)));

#define NB 128
#define NT 512
#define Ln 500
#define Hn 512
#define LDn 256
#define UDn 128
#define Vn 33
#define Tn 500
#define SENT_V 0x9E3779B1u

// ---- workspace u32 offsets ----
#define W_INITC 0u
#define W_SENT  1u
#define W_GEM   64u        // f32 [33][1536]   embed@W_ih^T + b_ih
#define W_M2    50752u     // f32 [512 j][128 u] catW_right@memW
#define W_CB    116288u    // f32 [512]        cat_b + catWr@mem_b
#define W_END   116800u    // ~467 KB

__device__ __forceinline__ float b2f(u16 v) {
  u32 x = ((u32)v) << 16; float f; __builtin_memcpy(&f, &x, 4); return f;
}
__device__ __forceinline__ float bitsf(u32 x) {
  float f; __builtin_memcpy(&f, &x, 4); return f;
}
#define LO16(d) bitsf((u32)(d) << 16)
#define HI16(d) bitsf((u32)(d) & 0xffff0000u)
__device__ __forceinline__ u16 f2b(float f) {  // RNE
  u32 x; __builtin_memcpy(&x, &f, 4);
  x += 0x7fffu + ((x >> 16) & 1u);
  return (u16)(x >> 16);
}
// mode==1: buffer holds bf16; mode==0: fp32
__device__ __forceinline__ float ldv(const void* p, size_t i, int mode) {
  return mode ? b2f(((const u16*)p)[i]) : ((const float*)p)[i];
}
__device__ __forceinline__ u32 aload(u32* p) {
  return __hip_atomic_load(p, __ATOMIC_ACQUIRE, __HIP_MEMORY_SCOPE_AGENT);
}
__device__ __forceinline__ void waitGe(u32* p, u32 tgt) {
  while (aload(p) < tgt) __builtin_amdgcn_s_sleep(4);
}
__device__ __forceinline__ void arrive(u32* p) {
  __hip_atomic_fetch_add(p, 1u, __ATOMIC_RELEASE, __HIP_MEMORY_SCOPE_AGENT);
}
__device__ __forceinline__ void astore(u32* p, u32 v) {
  __hip_atomic_store(p, v, __ATOMIC_RELEASE, __HIP_MEMORY_SCOPE_AGENT);
}

extern "C" __global__ void __launch_bounds__(512, 2)
rnn_v7(const void* latent, const void* ulat, const void* embd,
       const void* hidW, const void* hidb, const void* memW, const void* memb,
       const void* Wih, const void* Whh, const void* bih, const void* bhh,
       const void* catW, const void* catb, const void* outW, const void* outb,
       void* out, u32* ws) {
  // ---- LDS: per-row persistent state + phase-local arena ----
  __shared__ __align__(16) u16  ulat_l[Ln * 130];  // 130000 B (mode1 only)
  __shared__ __align__(16) float h_l[Hn];          // 2048 B, live 500 steps
  __shared__ __align__(16) char  arena[12288];     // phase-local scratch
  __shared__ __align__(16) float bhh_l[1536];      // 6144 B
  __shared__ float misc_l[2];                      // [0]=s0 [1]=inv_sum
  __shared__ int   s_tok;
  __shared__ u32   s_det;

  const int tid = threadIdx.x, blk = blockIdx.x;
  const int wv = tid >> 6, lane = tid & 63;
  const int gtid = blk * NT + tid;

  // ---- dtype detection: embed row PAD=1 is zero iff bf16 (verbatim) ----
  if (tid == 0) s_det = 0u;
  __syncthreads();
  if (tid < 256) {
    u32 v = ((const u32*)embd)[256 + tid];
    if (v) atomicOr(&s_det, 1u);
  }
  __syncthreads();
  const int mode = (s_det == 0u) ? 1 : 0;

  float* GEM = (float*)(ws + W_GEM);
  float* M2  = (float*)(ws + W_M2);
  float* cbF = (float*)(ws + W_CB);

  // ---- arena views (byte offsets; phases barrier-separated) ----
  float* ghq   = (float*)arena;            // GRU: [1536] dot+bhh      6144 B
  float* ps    = (float*)arena;            // attn: [128]              [0,512)
  float* ss    = (float*)(arena + 512);    // attn: [500]              [512,2512)
  float* es    = (float*)(arena + 2560);   // attn: [500]
  float* Bpart = (float*)(arena + 4608);   // attn: [8][128]           [4608,8704)
  float* cuv   = (float*)(arena + 8704);   // attn: [128]              [8704,9216)
  float* ccs   = (float*)(arena + 4608);   // cc:  [512]               [4608,6656)
  float* lgs   = (float*)(arena + 6656);   // log: [16*34]             [6656,8832)

  // ======================= per-block private init ===========================
  if (mode) {  // row's ulat tile -> LDS (padded stride 130 for bank spread)
    const u16* src = (const u16*)ulat + (size_t)blk * Ln * UDn;
    for (int i = tid; i < Ln * UDn; i += NT) {
      int l = i >> 7, c = i & 127;
      ulat_l[l * 130 + c] = src[(size_t)l * UDn + c];
    }
  }
  for (int i = tid; i < 1536; i += NT) bhh_l[i] = ldv(bhh, i, mode);
  {  // h0 = latent @ hidW^T + hidb  (v4-exact order); tid covers 512 = Hn
    int k = tid;
    float a = ldv(hidb, k, mode);
    for (int q = 0; q < LDn; q++)
      a += ldv(latent, (size_t)blk * LDn + q, mode) * ldv(hidW, (size_t)k * LDn + q, mode);
    h_l[k] = a;
  }
  if (tid == 0) s_tok = 0;  // SOS

  // ======================= cooperative ws table build =======================
  if (gtid < 50688) {                                  // GEM = embed@Wih^T+bih
    int v = gtid / 1536, j = gtid - v * 1536;
    float a = ldv(bih, j, mode);
    for (int k = 0; k < Hn; k++)
      a += ldv(embd, (size_t)v * Hn + k, mode) * ldv(Wih, (size_t)j * Hn + k, mode);
    GEM[gtid] = a;
  }
  if (gtid < 65536) {                                  // M2[j][u] = catWr@memW
    int j = gtid >> 7, u = gtid & 127;
    float a = 0.f;
    for (int h = 0; h < Hn; h++)
      a += ldv(catW, (size_t)j * 1024 + 512 + h, mode) * ldv(memW, (size_t)h * UDn + u, mode);
    M2[(size_t)j * 128 + u] = a;
  }
  if (gtid < 512) {                                    // cbias
    int j = gtid;
    float a = ldv(catb, j, mode);
    for (int h = 0; h < Hn; h++)
      a += ldv(catW, (size_t)j * 1024 + 512 + h, mode) * ldv(memb, h, mode);
    cbF[j] = a;
  }
  __threadfence();
  __syncthreads();
  if (tid == 0) {  // poison-agnostic device barrier (proven pattern)
    if (blk == 0) {
      __hip_atomic_store(ws + W_INITC, 0u, __ATOMIC_RELAXED, __HIP_MEMORY_SCOPE_AGENT);
      astore(ws + W_SENT, SENT_V);
    }
    while (aload(ws + W_SENT) != SENT_V) __builtin_amdgcn_s_sleep(8);
    arrive(ws + W_INITC);
    waitGe(ws + W_INITC, NB);
  }
  __syncthreads();

  // ======================= 500 decode steps (no global sync) ================
  for (int t = 0; t < Tn; t++) {
    __syncthreads();  // s_tok + prev-step arena reads complete

    // ---- GRU dots: 3 full rows per thread (d, d+512, d+1024) --------------
    // Per-row chain is v4's exact order: per chunk c (64 k), descending fma
    // nest per k4 (ascending k4), chunk partials s += a in order, then +bhh.
    // h_l reads are wave-uniform broadcasts; 24 dwordx4 in flight per chunk.
    {
      float s0 = 0.f, s1 = 0.f, s2r = 0.f;
      if (mode) {
        const u4* w0 = (const u4*)Whh + (size_t)(tid)        * 64;
        const u4* w1 = (const u4*)Whh + (size_t)(tid + 512)  * 64;
        const u4* w2 = (const u4*)Whh + (size_t)(tid + 1024) * 64;
        for (int c = 0; c < 8; c++) {
          u4 qa[8], qb[8], qc[8];
#pragma unroll
          for (int i = 0; i < 8; i++) qa[i] = w0[c * 8 + i];
#pragma unroll
          for (int i = 0; i < 8; i++) qb[i] = w1[c * 8 + i];
#pragma unroll
          for (int i = 0; i < 8; i++) qc[i] = w2[c * 8 + i];
          float a0 = 0.f, a1 = 0.f, a2 = 0.f;
#pragma unroll
          for (int b = 0; b < 2; b++) {
#pragma unroll
            for (int s2 = 0; s2 < 4; s2++) {
              const f4 xa = *(const f4*)(h_l + c * 64 + (b * 8 + s2 * 2) * 4);
              const f4 xb = *(const f4*)(h_l + c * 64 + (b * 8 + s2 * 2 + 1) * 4);
              const u4 q0 = qa[b * 4 + s2];
              a0 = fmaf(LO16(q0.x), xa.x, fmaf(HI16(q0.x), xa.y,
                   fmaf(LO16(q0.y), xa.z, fmaf(HI16(q0.y), xa.w, a0))));
              a0 = fmaf(LO16(q0.z), xb.x, fmaf(HI16(q0.z), xb.y,
                   fmaf(LO16(q0.w), xb.z, fmaf(HI16(q0.w), xb.w, a0))));
              const u4 q1 = qb[b * 4 + s2];
              a1 = fmaf(LO16(q1.x), xa.x, fmaf(HI16(q1.x), xa.y,
                   fmaf(LO16(q1.y), xa.z, fmaf(HI16(q1.y), xa.w, a1))));
              a1 = fmaf(LO16(q1.z), xb.x, fmaf(HI16(q1.z), xb.y,
                   fmaf(LO16(q1.w), xb.z, fmaf(HI16(q1.w), xb.w, a1))));
              const u4 q2 = qc[b * 4 + s2];
              a2 = fmaf(LO16(q2.x), xa.x, fmaf(HI16(q2.x), xa.y,
                   fmaf(LO16(q2.y), xa.z, fmaf(HI16(q2.y), xa.w, a2))));
              a2 = fmaf(LO16(q2.z), xb.x, fmaf(HI16(q2.z), xb.y,
                   fmaf(LO16(q2.w), xb.z, fmaf(HI16(q2.w), xb.w, a2))));
            }
          }
          s0 += a0; s1 += a1; s2r += a2;
        }
      } else {
        const f4* w0 = (const f4*)Whh + (size_t)(tid)        * 128;
        const f4* w1 = (const f4*)Whh + (size_t)(tid + 512)  * 128;
        const f4* w2 = (const f4*)Whh + (size_t)(tid + 1024) * 128;
        for (int c = 0; c < 8; c++) {
          f4 qa[16], qb[16], qc[16];
#pragma unroll
          for (int i = 0; i < 16; i++) qa[i] = w0[c * 16 + i];
#pragma unroll
          for (int i = 0; i < 16; i++) qb[i] = w1[c * 16 + i];
#pragma unroll
          for (int i = 0; i < 16; i++) qc[i] = w2[c * 16 + i];
          float a0 = 0.f, a1 = 0.f, a2 = 0.f;
#pragma unroll
          for (int k4 = 0; k4 < 16; k4++) {
            const f4 x = *(const f4*)(h_l + c * 64 + k4 * 4);
            const f4 qq0 = qa[k4];
            a0 = fmaf(qq0.x, x.x, fmaf(qq0.y, x.y, fmaf(qq0.z, x.z, fmaf(qq0.w, x.w, a0))));
            const f4 qq1 = qb[k4];
            a1 = fmaf(qq1.x, x.x, fmaf(qq1.y, x.y, fmaf(qq1.z, x.z, fmaf(qq1.w, x.w, a1))));
            const f4 qq2 = qc[k4];
            a2 = fmaf(qq2.x, x.x, fmaf(qq2.y, x.y, fmaf(qq2.z, x.z, fmaf(qq2.w, x.w, a2))));
          }
          s0 += a0; s1 += a1; s2r += a2;
        }
      }
      ghq[tid]        = s0  + bhh_l[tid];
      ghq[tid + 512]  = s1  + bhh_l[tid + 512];
      ghq[tid + 1024] = s2r + bhh_l[tid + 1024];
    }
    __syncthreads();

    // ---- gate nonlinearity + h update (verbatim v4 formulas) --------------
    float hnew;
    {
      const int j = tid;
      int tk = s_tok;
      if ((unsigned)tk > 32u) tk = 0;  // defensive clamp
      const float giR = GEM[tk * 1536 + j];
      const float giZ = GEM[tk * 1536 + 512 + j];
      const float giN = GEM[tk * 1536 + 1024 + j];
      const float rr = 1.f / (1.f + expf(-(giR + ghq[j])));
      const float zz = 1.f / (1.f + expf(-(giZ + ghq[512 + j])));
      const float nn = tanhf(giN + rr * ghq[1024 + j]);
      const float hv = h_l[j];
      hnew = (1.f - zz) * nn + zz * hv;
    }
    __syncthreads();
    h_l[tid] = hnew;
    __syncthreads();

    // ---- attention: p = memW^T h_new (v4 chains; 2 chunks per thread) -----
    {
      const int u = tid & 127, c8 = tid >> 7;  // c8 in 0..3; also do c8+4
      float aa = 0.f, ab = 0.f;
      if (mode) {
        const u16* mw = (const u16*)memW + u;
#pragma unroll 8
        for (int k = c8 * 64; k < c8 * 64 + 64; k++)
          aa = fmaf(b2f(mw[(size_t)k * UDn]), h_l[k], aa);
#pragma unroll 8
        for (int k = (c8 + 4) * 64; k < (c8 + 4) * 64 + 64; k++)
          ab = fmaf(b2f(mw[(size_t)k * UDn]), h_l[k], ab);
      } else {
        const float* mw = (const float*)memW + u;
#pragma unroll 8
        for (int k = c8 * 64; k < c8 * 64 + 64; k++)
          aa = fmaf(mw[(size_t)k * UDn], h_l[k], aa);
#pragma unroll 8
        for (int k = (c8 + 4) * 64; k < (c8 + 4) * 64 + 64; k++)
          ab = fmaf(mw[(size_t)k * UDn], h_l[k], ab);
      }
      Bpart[c8 * UDn + u] = aa;
      Bpart[(c8 + 4) * UDn + u] = ab;
    }
    __syncthreads();
    if (tid < 128) {
      float s = 0.f;
#pragma unroll
      for (int c = 0; c < 8; c++) s += Bpart[c * UDn + tid];
      ps[tid] = s;
    } else if (tid < 192) {  // s0 = h_new . mem_b
      const int ln = tid - 128;
      float a = 0.f;
#pragma unroll
      for (int i = 0; i < 8; i++) { int k = ln + i * 64; a = fmaf(h_l[k], ldv(memb, k, mode), a); }
      for (int o = 32; o; o >>= 1) a += __shfl_down(a, o);
      if (ln == 0) misc_l[0] = a;
    }
    __syncthreads();

    // ---- scores[l] = p . ul[l] + s0 (verbatim chains; 2 l per thread) -----
#pragma unroll
    for (int rep = 0; rep < 2; rep++) {
      const int l = (wv << 5) + (lane >> 1) + rep * 256, uh = lane & 1;
      float val = 0.f;
      if (l < Ln) {
        if (mode) {
          const u32* q = (const u32*)ulat_l + l * 65 + uh * 32;
          for (int i = 0; i < 32; i++) {
            const u32 d = q[i];
            val = fmaf(bitsf(d << 16), ps[uh * 64 + i * 2], val);
            val = fmaf(bitsf(d & 0xffff0000u), ps[uh * 64 + i * 2 + 1], val);
          }
        } else {
          const float* q = (const float*)ulat + ((size_t)blk * Ln + l) * UDn + uh * 64;
          for (int i = 0; i < 64; i++) val = fmaf(q[i], ps[uh * 64 + i], val);
        }
      }
      const float v2v = __shfl_down(val, 1);
      if ((lane & 1) == 0 && l < Ln) ss[l] = val + v2v + misc_l[0];
    }
    __syncthreads();
    if (wv == 0) {  // softmax stats over 500 (verbatim)
      float mx = -3.4e38f;
      for (int i = 0; i < 8; i++) {
        int l = lane + (i << 6);
        if (l < Ln) mx = fmaxf(mx, ss[l]);
      }
      for (int o = 32; o; o >>= 1) mx = fmaxf(mx, __shfl_xor(mx, o));
      float sum = 0.f;
      for (int i = 0; i < 8; i++) {
        int l = lane + (i << 6);
        if (l < Ln) { float e = expf(ss[l] - mx); es[l] = e; sum += e; }
      }
      for (int o = 32; o; o >>= 1) sum += __shfl_xor(sum, o);
      if (lane == 0) misc_l[1] = 1.f / sum;
    }
    __syncthreads();

    // ---- cu[u] = inv * sum_l es[l] * ul[l][u] (v4 chains; 2 per thread) ---
    {
      const int u = tid & 127, lc = tid >> 7;  // lc in 0..3; also lc+4
      float aa = 0.f, ab = 0.f;
      if (mode) {
        const int e0 = (lc * 64 + 64 < Ln) ? lc * 64 + 64 : Ln;
#pragma unroll 8
        for (int l = lc * 64; l < e0; l++) aa = fmaf(es[l], b2f(ulat_l[l * 130 + u]), aa);
        const int e1 = ((lc + 4) * 64 + 64 < Ln) ? (lc + 4) * 64 + 64 : Ln;
#pragma unroll 8
        for (int l = (lc + 4) * 64; l < e1; l++) ab = fmaf(es[l], b2f(ulat_l[l * 130 + u]), ab);
      } else {
        const float* q = (const float*)ulat + ((size_t)blk * Ln) * UDn + u;
        const int e0 = (lc * 64 + 64 < Ln) ? lc * 64 + 64 : Ln;
#pragma unroll 8
        for (int l = lc * 64; l < e0; l++) aa = fmaf(es[l], q[(size_t)l * UDn], aa);
        const int e1 = ((lc + 4) * 64 + 64 < Ln) ? (lc + 4) * 64 + 64 : Ln;
#pragma unroll 8
        for (int l = (lc + 4) * 64; l < e1; l++) ab = fmaf(es[l], q[(size_t)l * UDn], ab);
      }
      Bpart[lc * UDn + u] = aa;
      Bpart[(lc + 4) * UDn + u] = ab;
    }
    __syncthreads();
    if (tid < 128) {
      float s = 0.f;
#pragma unroll
      for (int c = 0; c < 8; c++) s += Bpart[c * UDn + tid];
      cuv[tid] = s * misc_l[1];
    }
    __syncthreads();

    // ---- cc = tanh(catWl.h + M2.cu + cbias): both halves per thread -------
    // Exact v4/v5 per-half chains a0 (hf=0), a1 (hf=1); combined as
    // (a0 + a1) + cb  ==  ccp2[j*2]+ccp2[j*2+1]+cbF[j]  (bit-identical).
    {
      const int j = tid;
      float a0 = 0.f, a1 = 0.f;
      if (mode) {
        const u4* cw = (const u4*)((const u16*)catW + (size_t)j * 1024);
        for (int b2 = 0; b2 < 4; b2++) {
          u4 q0[8], q1[8];
#pragma unroll
          for (int s2 = 0; s2 < 8; s2++) q0[s2] = cw[b2 * 8 + s2];
#pragma unroll
          for (int s2 = 0; s2 < 8; s2++) q1[s2] = cw[32 + b2 * 8 + s2];
#pragma unroll
          for (int s2 = 0; s2 < 8; s2++) {
            const int e0 = b2 * 64 + s2 * 8;
            const f4 xa = *(const f4*)(h_l + e0), xb = *(const f4*)(h_l + e0 + 4);
            a0 = fmaf(LO16(q0[s2].x), xa.x, a0); a0 = fmaf(HI16(q0[s2].x), xa.y, a0);
            a0 = fmaf(LO16(q0[s2].y), xa.z, a0); a0 = fmaf(HI16(q0[s2].y), xa.w, a0);
            a0 = fmaf(LO16(q0[s2].z), xb.x, a0); a0 = fmaf(HI16(q0[s2].z), xb.y, a0);
            a0 = fmaf(LO16(q0[s2].w), xb.z, a0); a0 = fmaf(HI16(q0[s2].w), xb.w, a0);
            const int e1 = 256 + b2 * 64 + s2 * 8;
            const f4 ya = *(const f4*)(h_l + e1), yb = *(const f4*)(h_l + e1 + 4);
            a1 = fmaf(LO16(q1[s2].x), ya.x, a1); a1 = fmaf(HI16(q1[s2].x), ya.y, a1);
            a1 = fmaf(LO16(q1[s2].y), ya.z, a1); a1 = fmaf(HI16(q1[s2].y), ya.w, a1);
            a1 = fmaf(LO16(q1[s2].z), yb.x, a1); a1 = fmaf(HI16(q1[s2].z), yb.y, a1);
            a1 = fmaf(LO16(q1[s2].w), yb.z, a1); a1 = fmaf(HI16(q1[s2].w), yb.w, a1);
          }
        }
      } else {
        const f4* cw4 = (const f4*)catW + (size_t)j * 256;
        for (int b2 = 0; b2 < 8; b2++) {
          f4 q0[8], q1[8];
#pragma unroll
          for (int s2 = 0; s2 < 8; s2++) q0[s2] = cw4[b2 * 8 + s2];
#pragma unroll
          for (int s2 = 0; s2 < 8; s2++) q1[s2] = cw4[64 + b2 * 8 + s2];
#pragma unroll
          for (int s2 = 0; s2 < 8; s2++) {
            const int e0 = b2 * 32 + s2 * 4;
            const f4 xa = *(const f4*)(h_l + e0);
            a0 = fmaf(q0[s2].x, xa.x, a0); a0 = fmaf(q0[s2].y, xa.y, a0);
            a0 = fmaf(q0[s2].z, xa.z, a0); a0 = fmaf(q0[s2].w, xa.w, a0);
            const int e1 = 256 + b2 * 32 + s2 * 4;
            const f4 ya = *(const f4*)(h_l + e1);
            a1 = fmaf(q1[s2].x, ya.x, a1); a1 = fmaf(q1[s2].y, ya.y, a1);
            a1 = fmaf(q1[s2].z, ya.z, a1); a1 = fmaf(q1[s2].w, ya.w, a1);
          }
        }
      }
      {  // M2 part (f32, ascending — v4-exact, appended per half)
        const f4* m2 = (const f4*)(M2 + (size_t)j * 128);
#pragma unroll
        for (int b2 = 0; b2 < 2; b2++) {
          f4 q0[8], q1[8];
#pragma unroll
          for (int s2 = 0; s2 < 8; s2++) q0[s2] = m2[b2 * 8 + s2];
#pragma unroll
          for (int s2 = 0; s2 < 8; s2++) q1[s2] = m2[16 + b2 * 8 + s2];
#pragma unroll
          for (int s2 = 0; s2 < 8; s2++) {
            const int e0 = b2 * 32 + s2 * 4;
            const f4 xc = *(const f4*)(cuv + e0);
            a0 = fmaf(q0[s2].x, xc.x, a0); a0 = fmaf(q0[s2].y, xc.y, a0);
            a0 = fmaf(q0[s2].z, xc.z, a0); a0 = fmaf(q0[s2].w, xc.w, a0);
            const int e1 = 64 + b2 * 32 + s2 * 4;
            const f4 yc = *(const f4*)(cuv + e1);
            a1 = fmaf(q1[s2].x, yc.x, a1); a1 = fmaf(q1[s2].y, yc.y, a1);
            a1 = fmaf(q1[s2].z, yc.z, a1); a1 = fmaf(q1[s2].w, yc.w, a1);
          }
        }
      }
      ccs[j] = tanhf(a0 + a1 + cbF[j]);
    }
    __syncthreads();

    // ---- logits + argmax + output (verbatim chains; 2 j0 per wave) --------
#pragma unroll
    for (int rep = 0; rep < 2; rep++) {
      if (lane < Vn) {
        const int w2i = wv + rep * 8;
        const int j0 = w2i << 5;
        float part = 0.f;
#pragma unroll
        for (int q = 0; q < 32; q++)
          part = fmaf(ccs[j0 + q], ldv(outW, (size_t)lane * Hn + j0 + q, mode), part);
        lgs[w2i * 34 + lane] = part;
      }
    }
    __syncthreads();
    if (wv == 0) {
      float lg = -3.4e38f;
      int idx = 0;
      if (lane < Vn) {
        float s = ldv(outb, lane, mode);
#pragma unroll
        for (int w2 = 0; w2 < 16; w2++) s += lgs[w2 * 34 + lane];
        if (mode) ((u16*)out)[(size_t)blk * (Vn * Ln) + lane * Ln + t] = f2b(s);
        else ((float*)out)[(size_t)blk * (Vn * Ln) + lane * Ln + t] = s;
        lg = s;
        idx = lane;
      }
      for (int o = 32; o; o >>= 1) {  // np argmax: first max wins
        const float ov = __shfl_down(lg, o);
        const int oi = __shfl_down(idx, o);
        if (ov > lg || (ov == lg && oi < idx)) { lg = ov; idx = oi; }
      }
      if (lane == 0) s_tok = idx;
    }
  }
}

extern "C" void kernel_launch(void* const* d_in, const int* in_sizes, int n_in,
                              void* d_out, int out_size, void* d_ws, size_t ws_size,
                              hipStream_t stream) {
  (void)in_sizes; (void)n_in; (void)out_size;
  if (ws_size < (size_t)W_END * 4) return;  // needs ~0.5 MB scratch
  hipLaunchKernelGGL(rnn_v7, dim3(NB), dim3(NT), 0, stream,
                     d_in[0],   // latent
                     d_in[1],   // upsampled_latent
                     d_in[3],   // embed (d_in[2]=target unused in eval)
                     d_in[4],   // hid_W
                     d_in[5],   // hid_b
                     d_in[6],   // mem_W
                     d_in[7],   // mem_b
                     d_in[8],   // W_ih
                     d_in[9],   // W_hh
                     d_in[10],  // b_ih
                     d_in[11],  // b_hh
                     d_in[12],  // cat_W
                     d_in[13],  // cat_b
                     d_in[14],  // out_W
                     d_in[15],  // out_b
                     d_out, (u32*)d_ws);
}

// Round 6
// 85835.590 us; speedup vs baseline: 1.1799x; 1.1799x over previous
//
#include <hip/hip_runtime.h>
#include <hip/hip_bf16.h>
#include <math.h>

// ============================================================================
// RNNDecoder v8: 128 independent persistent blocks (one row/block, no
// inter-block sync), NT=512. GRU weight stream (1.5 MB/step, 63% of traffic)
// now flows through a per-wave double-buffered global_load_lds pipeline:
// wave stages 8 rows (8 KB, 8 insts) for tile t+1 while computing tile t from
// LDS; s_waitcnt vmcnt(8) between (counted-vmcnt, never-drain pattern). Data
// never touches VGPRs -> MLP is no longer register-bound (v5-v7 failure).
// LDS reads conflict-free via XOR slot swizzle applied on the per-lane GLOBAL
// source (linear LDS dest, global_load_lds requirement). ulat reads moved to
// global (v2's exact chains) freeing 130 KB LDS for the staging dbuf. All
// accumulation chains element-identical to the passing v4/v5 trajectory.
// ============================================================================

typedef unsigned short u16;
typedef unsigned int u32;
typedef float f4 __attribute__((ext_vector_type(4)));
typedef u32 u4 __attribute__((ext_vector_type(4)));

#define NB 128
#define NT 512
#define Ln 500
#define Hn 512
#define LDn 256
#define UDn 128
#define Vn 33
#define Tn 500
#define SENT_V 0x9E3779B1u

// ---- workspace u32 offsets ----
#define W_INITC 0u
#define W_SENT  1u
#define W_GEM   64u        // f32 [33][1536]   embed@W_ih^T + b_ih
#define W_M2    50752u     // f32 [512 j][128 u] catW_right@memW
#define W_CB    116288u    // f32 [512]        cat_b + catWr@mem_b
#define W_END   116800u    // ~467 KB

__device__ __forceinline__ float b2f(u16 v) {
  u32 x = ((u32)v) << 16; float f; __builtin_memcpy(&f, &x, 4); return f;
}
__device__ __forceinline__ float bitsf(u32 x) {
  float f; __builtin_memcpy(&f, &x, 4); return f;
}
#define LO16(d) bitsf((u32)(d) << 16)
#define HI16(d) bitsf((u32)(d) & 0xffff0000u)
__device__ __forceinline__ u16 f2b(float f) {  // RNE
  u32 x; __builtin_memcpy(&x, &f, 4);
  x += 0x7fffu + ((x >> 16) & 1u);
  return (u16)(x >> 16);
}
// mode==1: buffer holds bf16; mode==0: fp32
__device__ __forceinline__ float ldv(const void* p, size_t i, int mode) {
  return mode ? b2f(((const u16*)p)[i]) : ((const float*)p)[i];
}
__device__ __forceinline__ u32 aload(u32* p) {
  return __hip_atomic_load(p, __ATOMIC_ACQUIRE, __HIP_MEMORY_SCOPE_AGENT);
}
__device__ __forceinline__ void waitGe(u32* p, u32 tgt) {
  while (aload(p) < tgt) __builtin_amdgcn_s_sleep(4);
}
__device__ __forceinline__ void arrive(u32* p) {
  __hip_atomic_fetch_add(p, 1u, __ATOMIC_RELEASE, __HIP_MEMORY_SCOPE_AGENT);
}
__device__ __forceinline__ void astore(u32* p, u32 v) {
  __hip_atomic_store(p, v, __ATOMIC_RELEASE, __HIP_MEMORY_SCOPE_AGENT);
}
// async global->LDS: 16 B per lane; LDS dest = wave-uniform base + lane*16;
// global src is per-lane (carries the swizzle).
__device__ __forceinline__ void stage16(const void* g, void* l) {
  __builtin_amdgcn_global_load_lds(
      (const __attribute__((address_space(1))) u32*)g,
      (__attribute__((address_space(3))) u32*)l, 16, 0, 0);
}

extern "C" __global__ void __launch_bounds__(512, 2)
rnn_v8(const void* latent, const void* ulat, const void* embd,
       const void* hidW, const void* hidb, const void* memW, const void* memb,
       const void* Wih, const void* Whh, const void* bih, const void* bhh,
       const void* catW, const void* catb, const void* outW, const void* outb,
       void* out, u32* ws) {
  // ---- LDS ----
  __shared__ __align__(16) char  stage[131072];    // 2 x 64 KB staging dbuf
  __shared__ __align__(16) char  arena[12288];     // phase-local scratch
  __shared__ __align__(16) float bhh_l[1536];      // 6144 B
  __shared__ __align__(16) float h_l[Hn];          // 2048 B, live 500 steps
  __shared__ float misc_l[2];                      // [0]=s0 [1]=inv_sum
  __shared__ int   s_tok;
  __shared__ u32   s_det;

  const int tid = threadIdx.x, blk = blockIdx.x;
  const int wv = tid >> 6, lane = tid & 63;
  const int gtid = blk * NT + tid;

  // ---- dtype detection: embed row PAD=1 is zero iff bf16 (verbatim) ----
  if (tid == 0) s_det = 0u;
  __syncthreads();
  if (tid < 256) {
    u32 v = ((const u32*)embd)[256 + tid];
    if (v) atomicOr(&s_det, 1u);
  }
  __syncthreads();
  const int mode = (s_det == 0u) ? 1 : 0;

  float* GEM = (float*)(ws + W_GEM);
  float* M2  = (float*)(ws + W_M2);
  float* cbF = (float*)(ws + W_CB);

  // ---- arena views (byte offsets; phases barrier-separated) ----
  float* ghq   = (float*)arena;            // GRU: [1536] dot+bhh      6144 B
  float* ps    = (float*)arena;            // attn: [128]              [0,512)
  float* ss    = (float*)(arena + 512);    // attn: [500]
  float* es    = (float*)(arena + 2560);   // attn: [500]
  float* Bpart = (float*)(arena + 4608);   // attn: [8][128]
  float* cuv   = (float*)(arena + 8704);   // attn: [128]
  float* ccs   = (float*)(arena + 4608);   // cc:  [512]
  float* lgs   = (float*)(arena + 6656);   // log: [16*34]

  // ======================= per-block private init ===========================
  for (int i = tid; i < 1536; i += NT) bhh_l[i] = ldv(bhh, i, mode);
  {  // h0 = latent @ hidW^T + hidb  (v4-exact order); tid covers 512 = Hn
    int k = tid;
    float a = ldv(hidb, k, mode);
    for (int q = 0; q < LDn; q++)
      a += ldv(latent, (size_t)blk * LDn + q, mode) * ldv(hidW, (size_t)k * LDn + q, mode);
    h_l[k] = a;
  }
  if (tid == 0) s_tok = 0;  // SOS

  // ======================= cooperative ws table build =======================
  if (gtid < 50688) {                                  // GEM = embed@Wih^T+bih
    int v = gtid / 1536, j = gtid - v * 1536;
    float a = ldv(bih, j, mode);
    for (int k = 0; k < Hn; k++)
      a += ldv(embd, (size_t)v * Hn + k, mode) * ldv(Wih, (size_t)j * Hn + k, mode);
    GEM[gtid] = a;
  }
  if (gtid < 65536) {                                  // M2[j][u] = catWr@memW
    int j = gtid >> 7, u = gtid & 127;
    float a = 0.f;
    for (int h = 0; h < Hn; h++)
      a += ldv(catW, (size_t)j * 1024 + 512 + h, mode) * ldv(memW, (size_t)h * UDn + u, mode);
    M2[(size_t)j * 128 + u] = a;
  }
  if (gtid < 512) {                                    // cbias
    int j = gtid;
    float a = ldv(catb, j, mode);
    for (int h = 0; h < Hn; h++)
      a += ldv(catW, (size_t)j * 1024 + 512 + h, mode) * ldv(memb, h, mode);
    cbF[j] = a;
  }
  __threadfence();
  __syncthreads();
  if (tid == 0) {  // poison-agnostic device barrier (proven pattern)
    if (blk == 0) {
      __hip_atomic_store(ws + W_INITC, 0u, __ATOMIC_RELAXED, __HIP_MEMORY_SCOPE_AGENT);
      astore(ws + W_SENT, SENT_V);
    }
    while (aload(ws + W_SENT) != SENT_V) __builtin_amdgcn_s_sleep(8);
    arrive(ws + W_INITC);
    waitGe(ws + W_INITC, NB);
  }
  __syncthreads();

  // ======================= 500 decode steps (no global sync) ================
  for (int t = 0; t < Tn; t++) {
    __syncthreads();  // s_tok + prev-step arena reads complete

    // ---- GRU: per-wave double-buffered global_load_lds pipeline -----------
    // Wave w owns rows {tile*R + w*r + r'} (disjoint across waves: no
    // barriers in the tile loop). Compute lane (r'=lane>>3, c=lane&7) runs
    // v4/v5's exact 64-element chunk chain + in-order shfl fold.
    {
      const int c = lane & 7;
      f4 xv[16];  // this lane's h chunk (c*64..c*64+64), loaded once per step
#pragma unroll
      for (int i = 0; i < 16; i++) xv[i] = *(const f4*)(h_l + c * 64 + i * 4);
      const int base = lane & 56;
      if (mode) {
        // swizzled per-lane source: stage lane (cs=lane>>3, j=lane&7) holds
        // global element-block (j^cs) of chunk cs -> read slot (i^c) = elem i.
        const u32 soff = (u32)((lane >> 3) * 128 + (((lane & 7) ^ (lane >> 3)) * 16));
        const char* W = (const char*)Whh;
        const int rp = lane >> 3;
#pragma unroll
        for (int r = 0; r < 8; r++)  // prologue: tile 0
          stage16(W + (size_t)(wv * 8 + r) * 1024 + soff,
                  stage + (size_t)(wv * 8 + r) * 1024);
        for (int tt = 0; tt < 24; tt++) {
          if (tt < 23) {
            char* nbuf = stage + (size_t)((tt + 1) & 1) * 65536;
#pragma unroll
            for (int r = 0; r < 8; r++)
              stage16(W + (size_t)((tt + 1) * 64 + wv * 8 + r) * 1024 + soff,
                      nbuf + (size_t)(wv * 8 + r) * 1024);
            asm volatile("s_waitcnt vmcnt(8)" ::: "memory");
          } else {
            asm volatile("s_waitcnt vmcnt(0)" ::: "memory");
          }
          const char* rb = stage + (size_t)(tt & 1) * 65536 +
                           (size_t)(wv * 8 + rp) * 1024 + c * 128;
          float a = 0.f;
#pragma unroll
          for (int s = 0; s < 8; s++) {  // v4/v5-exact chunk chain
            const u4 q = *(const u4*)(rb + ((s ^ c) * 16));
            const f4 xa = xv[s * 2], xb = xv[s * 2 + 1];
            a = fmaf(LO16(q.x), xa.x, fmaf(HI16(q.x), xa.y,
                fmaf(LO16(q.y), xa.z, fmaf(HI16(q.y), xa.w, a))));
            a = fmaf(LO16(q.z), xb.x, fmaf(HI16(q.z), xb.y,
                fmaf(LO16(q.w), xb.z, fmaf(HI16(q.w), xb.w, a))));
          }
          float sf = __shfl(a, base);  // in-order fold == v4's s += a_c
#pragma unroll
          for (int c2 = 1; c2 < 8; c2++) sf += __shfl(a, base + c2);
          if (c == 0) {
            const int d = tt * 64 + wv * 8 + rp;
            ghq[d] = sf + bhh_l[d];
          }
        }
      } else {
        // f32: 32-row tiles (64 KB), wave owns 4 rows, lanes<32 compute.
        const u32 l4 = (u32)(lane & 15);
        const u32 cs0 = (u32)(lane >> 4), cs1 = cs0 + 4;
        const u32 soff0 = cs0 * 256 + (((l4 & 8) | ((l4 ^ cs0) & 7))) * 16;
        const u32 soff1 = cs1 * 256 + (((l4 & 8) | ((l4 ^ cs1) & 7))) * 16;
        const char* W = (const char*)Whh;
        const int rp = lane >> 3, act = (lane < 32);
#pragma unroll
        for (int r = 0; r < 4; r++) {  // prologue: tile 0
          const char* src = W + (size_t)(wv * 4 + r) * 2048;
          char* dst = stage + (size_t)(wv * 4 + r) * 2048;
          stage16(src + soff0, dst);
          stage16(src + soff1, dst + 1024);
        }
        for (int tt = 0; tt < 48; tt++) {
          if (tt < 47) {
            char* nbuf = stage + (size_t)((tt + 1) & 1) * 65536;
#pragma unroll
            for (int r = 0; r < 4; r++) {
              const char* src = W + (size_t)((tt + 1) * 32 + wv * 4 + r) * 2048;
              char* dst = nbuf + (size_t)(wv * 4 + r) * 2048;
              stage16(src + soff0, dst);
              stage16(src + soff1, dst + 1024);
            }
            asm volatile("s_waitcnt vmcnt(8)" ::: "memory");
          } else {
            asm volatile("s_waitcnt vmcnt(0)" ::: "memory");
          }
          if (act) {
            const char* rb = stage + (size_t)(tt & 1) * 65536 +
                             (size_t)(wv * 4 + rp) * 2048 + c * 256;
            float a = 0.f;
#pragma unroll
            for (int i = 0; i < 16; i++) {  // v4-exact chunk chain (f32)
              const u32 j = (u32)((i & 8) | ((i ^ c) & 7));
              const f4 q = *(const f4*)(rb + j * 16);
              const f4 x = xv[i];
              a = fmaf(q.x, x.x, fmaf(q.y, x.y, fmaf(q.z, x.z, fmaf(q.w, x.w, a))));
            }
            float sf = __shfl(a, base);
#pragma unroll
            for (int c2 = 1; c2 < 8; c2++) sf += __shfl(a, base + c2);
            if (c == 0) {
              const int d = tt * 32 + wv * 4 + rp;
              ghq[d] = sf + bhh_l[d];
            }
          }
        }
      }
    }
    __syncthreads();

    // ---- gate nonlinearity + h update (verbatim v4 formulas) --------------
    float hnew;
    {
      const int j = tid;
      int tk = s_tok;
      if ((unsigned)tk > 32u) tk = 0;  // defensive clamp
      const float giR = GEM[tk * 1536 + j];
      const float giZ = GEM[tk * 1536 + 512 + j];
      const float giN = GEM[tk * 1536 + 1024 + j];
      const float rr = 1.f / (1.f + expf(-(giR + ghq[j])));
      const float zz = 1.f / (1.f + expf(-(giZ + ghq[512 + j])));
      const float nn = tanhf(giN + rr * ghq[1024 + j]);
      const float hv = h_l[j];
      hnew = (1.f - zz) * nn + zz * hv;
    }
    __syncthreads();
    h_l[tid] = hnew;
    __syncthreads();

    // ---- attention: p = memW^T h_new (v4 chains; 2 chunks per thread) -----
    {
      const int u = tid & 127, c8 = tid >> 7;  // c8 in 0..3; also do c8+4
      float aa = 0.f, ab = 0.f;
      if (mode) {
        const u16* mw = (const u16*)memW + u;
#pragma unroll 8
        for (int k = c8 * 64; k < c8 * 64 + 64; k++)
          aa = fmaf(b2f(mw[(size_t)k * UDn]), h_l[k], aa);
#pragma unroll 8
        for (int k = (c8 + 4) * 64; k < (c8 + 4) * 64 + 64; k++)
          ab = fmaf(b2f(mw[(size_t)k * UDn]), h_l[k], ab);
      } else {
        const float* mw = (const float*)memW + u;
#pragma unroll 8
        for (int k = c8 * 64; k < c8 * 64 + 64; k++)
          aa = fmaf(mw[(size_t)k * UDn], h_l[k], aa);
#pragma unroll 8
        for (int k = (c8 + 4) * 64; k < (c8 + 4) * 64 + 64; k++)
          ab = fmaf(mw[(size_t)k * UDn], h_l[k], ab);
      }
      Bpart[c8 * UDn + u] = aa;
      Bpart[(c8 + 4) * UDn + u] = ab;
    }
    __syncthreads();
    if (tid < 128) {
      float s = 0.f;
#pragma unroll
      for (int c = 0; c < 8; c++) s += Bpart[c * UDn + tid];
      ps[tid] = s;
    } else if (tid < 192) {  // s0 = h_new . mem_b
      const int ln = tid - 128;
      float a = 0.f;
#pragma unroll
      for (int i = 0; i < 8; i++) { int k = ln + i * 64; a = fmaf(h_l[k], ldv(memb, k, mode), a); }
      for (int o = 32; o; o >>= 1) a += __shfl_down(a, o);
      if (ln == 0) misc_l[0] = a;
    }
    __syncthreads();

    // ---- scores[l] = p . ul[l] + s0 (v2-exact chains, global ulat) --------
#pragma unroll
    for (int rep = 0; rep < 2; rep++) {
      const int l = (wv << 5) + (lane >> 1) + rep * 256, uh = lane & 1;
      float val = 0.f;
      if (l < Ln) {
        if (mode) {
          const u32* q = (const u32*)ulat + ((size_t)blk * Ln + l) * 64 + uh * 32;
#pragma unroll 8
          for (int i = 0; i < 32; i++) {
            const u32 d = q[i];
            val = fmaf(bitsf(d << 16), ps[uh * 64 + i * 2], val);
            val = fmaf(bitsf(d & 0xffff0000u), ps[uh * 64 + i * 2 + 1], val);
          }
        } else {
          const float* q = (const float*)ulat + ((size_t)blk * Ln + l) * UDn + uh * 64;
#pragma unroll 8
          for (int i = 0; i < 64; i++) val = fmaf(q[i], ps[uh * 64 + i], val);
        }
      }
      const float v2v = __shfl_down(val, 1);
      if ((lane & 1) == 0 && l < Ln) ss[l] = val + v2v + misc_l[0];
    }
    __syncthreads();
    if (wv == 0) {  // softmax stats over 500 (verbatim)
      float mx = -3.4e38f;
      for (int i = 0; i < 8; i++) {
        int l = lane + (i << 6);
        if (l < Ln) mx = fmaxf(mx, ss[l]);
      }
      for (int o = 32; o; o >>= 1) mx = fmaxf(mx, __shfl_xor(mx, o));
      float sum = 0.f;
      for (int i = 0; i < 8; i++) {
        int l = lane + (i << 6);
        if (l < Ln) { float e = expf(ss[l] - mx); es[l] = e; sum += e; }
      }
      for (int o = 32; o; o >>= 1) sum += __shfl_xor(sum, o);
      if (lane == 0) misc_l[1] = 1.f / sum;
    }
    __syncthreads();

    // ---- cu[u] = inv * sum_l es[l] * ul[l][u] (v2 chains, global ulat) ----
    {
      const int u = tid & 127, lc = tid >> 7;  // lc in 0..3; also lc+4
      float aa = 0.f, ab = 0.f;
      if (mode) {
        const u16* q = (const u16*)ulat + ((size_t)blk * Ln) * UDn + u;
        const int e0 = (lc * 64 + 64 < Ln) ? lc * 64 + 64 : Ln;
#pragma unroll 8
        for (int l = lc * 64; l < e0; l++) aa = fmaf(es[l], b2f(q[(size_t)l * UDn]), aa);
        const int e1 = ((lc + 4) * 64 + 64 < Ln) ? (lc + 4) * 64 + 64 : Ln;
#pragma unroll 8
        for (int l = (lc + 4) * 64; l < e1; l++) ab = fmaf(es[l], b2f(q[(size_t)l * UDn]), ab);
      } else {
        const float* q = (const float*)ulat + ((size_t)blk * Ln) * UDn + u;
        const int e0 = (lc * 64 + 64 < Ln) ? lc * 64 + 64 : Ln;
#pragma unroll 8
        for (int l = lc * 64; l < e0; l++) aa = fmaf(es[l], q[(size_t)l * UDn], aa);
        const int e1 = ((lc + 4) * 64 + 64 < Ln) ? (lc + 4) * 64 + 64 : Ln;
#pragma unroll 8
        for (int l = (lc + 4) * 64; l < e1; l++) ab = fmaf(es[l], q[(size_t)l * UDn], ab);
      }
      Bpart[lc * UDn + u] = aa;
      Bpart[(lc + 4) * UDn + u] = ab;
    }
    __syncthreads();
    if (tid < 128) {
      float s = 0.f;
#pragma unroll
      for (int c = 0; c < 8; c++) s += Bpart[c * UDn + tid];
      cuv[tid] = s * misc_l[1];
    }
    __syncthreads();

    // ---- cc = tanh(catWl.h + M2.cu + cbias): both halves per thread -------
    // Exact v4/v5 per-half chains a0 (hf=0), a1 (hf=1); (a0+a1)+cb identical.
    {
      const int j = tid;
      float a0 = 0.f, a1 = 0.f;
      if (mode) {
        const u4* cw = (const u4*)((const u16*)catW + (size_t)j * 1024);
        for (int b2 = 0; b2 < 4; b2++) {
          u4 q0[8], q1[8];
#pragma unroll
          for (int s2 = 0; s2 < 8; s2++) q0[s2] = cw[b2 * 8 + s2];
#pragma unroll
          for (int s2 = 0; s2 < 8; s2++) q1[s2] = cw[32 + b2 * 8 + s2];
#pragma unroll
          for (int s2 = 0; s2 < 8; s2++) {
            const int e0 = b2 * 64 + s2 * 8;
            const f4 xa = *(const f4*)(h_l + e0), xb = *(const f4*)(h_l + e0 + 4);
            a0 = fmaf(LO16(q0[s2].x), xa.x, a0); a0 = fmaf(HI16(q0[s2].x), xa.y, a0);
            a0 = fmaf(LO16(q0[s2].y), xa.z, a0); a0 = fmaf(HI16(q0[s2].y), xa.w, a0);
            a0 = fmaf(LO16(q0[s2].z), xb.x, a0); a0 = fmaf(HI16(q0[s2].z), xb.y, a0);
            a0 = fmaf(LO16(q0[s2].w), xb.z, a0); a0 = fmaf(HI16(q0[s2].w), xb.w, a0);
            const int e1 = 256 + b2 * 64 + s2 * 8;
            const f4 ya = *(const f4*)(h_l + e1), yb = *(const f4*)(h_l + e1 + 4);
            a1 = fmaf(LO16(q1[s2].x), ya.x, a1); a1 = fmaf(HI16(q1[s2].x), ya.y, a1);
            a1 = fmaf(LO16(q1[s2].y), ya.z, a1); a1 = fmaf(HI16(q1[s2].y), ya.w, a1);
            a1 = fmaf(LO16(q1[s2].z), yb.x, a1); a1 = fmaf(HI16(q1[s2].z), yb.y, a1);
            a1 = fmaf(LO16(q1[s2].w), yb.z, a1); a1 = fmaf(HI16(q1[s2].w), yb.w, a1);
          }
        }
      } else {
        const f4* cw4 = (const f4*)catW + (size_t)j * 256;
        for (int b2 = 0; b2 < 8; b2++) {
          f4 q0[8], q1[8];
#pragma unroll
          for (int s2 = 0; s2 < 8; s2++) q0[s2] = cw4[b2 * 8 + s2];
#pragma unroll
          for (int s2 = 0; s2 < 8; s2++) q1[s2] = cw4[64 + b2 * 8 + s2];
#pragma unroll
          for (int s2 = 0; s2 < 8; s2++) {
            const int e0 = b2 * 32 + s2 * 4;
            const f4 xa = *(const f4*)(h_l + e0);
            a0 = fmaf(q0[s2].x, xa.x, a0); a0 = fmaf(q0[s2].y, xa.y, a0);
            a0 = fmaf(q0[s2].z, xa.z, a0); a0 = fmaf(q0[s2].w, xa.w, a0);
            const int e1 = 256 + b2 * 32 + s2 * 4;
            const f4 ya = *(const f4*)(h_l + e1);
            a1 = fmaf(q1[s2].x, ya.x, a1); a1 = fmaf(q1[s2].y, ya.y, a1);
            a1 = fmaf(q1[s2].z, ya.z, a1); a1 = fmaf(q1[s2].w, ya.w, a1);
          }
        }
      }
      {  // M2 part (f32, ascending — v4-exact, appended per half)
        const f4* m2 = (const f4*)(M2 + (size_t)j * 128);
#pragma unroll
        for (int b2 = 0; b2 < 2; b2++) {
          f4 q0[8], q1[8];
#pragma unroll
          for (int s2 = 0; s2 < 8; s2++) q0[s2] = m2[b2 * 8 + s2];
#pragma unroll
          for (int s2 = 0; s2 < 8; s2++) q1[s2] = m2[16 + b2 * 8 + s2];
#pragma unroll
          for (int s2 = 0; s2 < 8; s2++) {
            const int e0 = b2 * 32 + s2 * 4;
            const f4 xc = *(const f4*)(cuv + e0);
            a0 = fmaf(q0[s2].x, xc.x, a0); a0 = fmaf(q0[s2].y, xc.y, a0);
            a0 = fmaf(q0[s2].z, xc.z, a0); a0 = fmaf(q0[s2].w, xc.w, a0);
            const int e1 = 64 + b2 * 32 + s2 * 4;
            const f4 yc = *(const f4*)(cuv + e1);
            a1 = fmaf(q1[s2].x, yc.x, a1); a1 = fmaf(q1[s2].y, yc.y, a1);
            a1 = fmaf(q1[s2].z, yc.z, a1); a1 = fmaf(q1[s2].w, yc.w, a1);
          }
        }
      }
      ccs[j] = tanhf(a0 + a1 + cbF[j]);
    }
    __syncthreads();

    // ---- logits + argmax + output (verbatim chains; 2 j0 per wave) --------
#pragma unroll
    for (int rep = 0; rep < 2; rep++) {
      if (lane < Vn) {
        const int w2i = wv + rep * 8;
        const int j0 = w2i << 5;
        float part = 0.f;
#pragma unroll
        for (int q = 0; q < 32; q++)
          part = fmaf(ccs[j0 + q], ldv(outW, (size_t)lane * Hn + j0 + q, mode), part);
        lgs[w2i * 34 + lane] = part;
      }
    }
    __syncthreads();
    if (wv == 0) {
      float lg = -3.4e38f;
      int idx = 0;
      if (lane < Vn) {
        float s = ldv(outb, lane, mode);
#pragma unroll
        for (int w2 = 0; w2 < 16; w2++) s += lgs[w2 * 34 + lane];
        if (mode) ((u16*)out)[(size_t)blk * (Vn * Ln) + lane * Ln + t] = f2b(s);
        else ((float*)out)[(size_t)blk * (Vn * Ln) + lane * Ln + t] = s;
        lg = s;
        idx = lane;
      }
      for (int o = 32; o; o >>= 1) {  // np argmax: first max wins
        const float ov = __shfl_down(lg, o);
        const int oi = __shfl_down(idx, o);
        if (ov > lg || (ov == lg && oi < idx)) { lg = ov; idx = oi; }
      }
      if (lane == 0) s_tok = idx;
    }
  }
}

extern "C" void kernel_launch(void* const* d_in, const int* in_sizes, int n_in,
                              void* d_out, int out_size, void* d_ws, size_t ws_size,
                              hipStream_t stream) {
  (void)in_sizes; (void)n_in; (void)out_size;
  if (ws_size < (size_t)W_END * 4) return;  // needs ~0.5 MB scratch
  hipLaunchKernelGGL(rnn_v8, dim3(NB), dim3(NT), 0, stream,
                     d_in[0],   // latent
                     d_in[1],   // upsampled_latent
                     d_in[3],   // embed (d_in[2]=target unused in eval)
                     d_in[4],   // hid_W
                     d_in[5],   // hid_b
                     d_in[6],   // mem_W
                     d_in[7],   // mem_b
                     d_in[8],   // W_ih
                     d_in[9],   // W_hh
                     d_in[10],  // b_ih
                     d_in[11],  // b_hh
                     d_in[12],  // cat_W
                     d_in[13],  // cat_b
                     d_in[14],  // out_W
                     d_in[15],  // out_b
                     d_out, (u32*)d_ws);
}

// Round 7
// 77444.946 us; speedup vs baseline: 1.3077x; 1.1083x over previous
//
#include <hip/hip_runtime.h>
#include <hip/hip_bf16.h>
#include <math.h>

// ============================================================================
// RNNDecoder v9: v8 (128 independent persistent blocks, GRU global_load_lds
// dbuf pipeline) + pipelining of the remaining big streams:
//  - cc: catW-left rows staged through the same 2x64KB dbuf (counted vmcnt(8),
//    raw s_barrier, wave tt computes 64 rows with v4's VERBATIM a0/a1 chain
//    from XOR-swizzled LDS slots; M2 part verbatim register chain).
//  - p: memW^T table (mWT, f32) in ws -> contiguous batched f4 reads, same
//    fma order.
//  - scores: batched dwordx4 ulat reads, same unpack/fma order.
// All accumulation chains element-for-element identical to the passing
// v4/v5/v8 trajectory. mode0 (f32 inputs) keeps v8's cc path.
// ============================================================================

typedef unsigned short u16;
typedef unsigned int u32;
typedef float f4 __attribute__((ext_vector_type(4)));
typedef u32 u4 __attribute__((ext_vector_type(4)));

#define NB 128
#define NT 512
#define Ln 500
#define Hn 512
#define LDn 256
#define UDn 128
#define Vn 33
#define Tn 500
#define SENT_V 0x9E3779B1u

// ---- workspace u32 offsets ----
#define W_INITC 0u
#define W_SENT  1u
#define W_GEM   64u        // f32 [33][1536]   embed@W_ih^T + b_ih
#define W_M2    50752u     // f32 [512 j][128 u] catW_right@memW
#define W_CB    116288u    // f32 [512]        cat_b + catWr@mem_b
#define W_MWT   116800u    // f32 [128 u][512 k] memW^T
#define W_END   182336u    // ~730 KB

__device__ __forceinline__ float b2f(u16 v) {
  u32 x = ((u32)v) << 16; float f; __builtin_memcpy(&f, &x, 4); return f;
}
__device__ __forceinline__ float bitsf(u32 x) {
  float f; __builtin_memcpy(&f, &x, 4); return f;
}
#define LO16(d) bitsf((u32)(d) << 16)
#define HI16(d) bitsf((u32)(d) & 0xffff0000u)
__device__ __forceinline__ u16 f2b(float f) {  // RNE
  u32 x; __builtin_memcpy(&x, &f, 4);
  x += 0x7fffu + ((x >> 16) & 1u);
  return (u16)(x >> 16);
}
// mode==1: buffer holds bf16; mode==0: fp32
__device__ __forceinline__ float ldv(const void* p, size_t i, int mode) {
  return mode ? b2f(((const u16*)p)[i]) : ((const float*)p)[i];
}
__device__ __forceinline__ u32 aload(u32* p) {
  return __hip_atomic_load(p, __ATOMIC_ACQUIRE, __HIP_MEMORY_SCOPE_AGENT);
}
__device__ __forceinline__ void waitGe(u32* p, u32 tgt) {
  while (aload(p) < tgt) __builtin_amdgcn_s_sleep(4);
}
__device__ __forceinline__ void arrive(u32* p) {
  __hip_atomic_fetch_add(p, 1u, __ATOMIC_RELEASE, __HIP_MEMORY_SCOPE_AGENT);
}
__device__ __forceinline__ void astore(u32* p, u32 v) {
  __hip_atomic_store(p, v, __ATOMIC_RELEASE, __HIP_MEMORY_SCOPE_AGENT);
}
// async global->LDS: 16 B per lane; LDS dest = wave-uniform base + lane*16;
// global src is per-lane (carries the swizzle).
__device__ __forceinline__ void stage16(const void* g, void* l) {
  __builtin_amdgcn_global_load_lds(
      (const __attribute__((address_space(1))) u32*)g,
      (__attribute__((address_space(3))) u32*)l, 16, 0, 0);
}

extern "C" __global__ void __launch_bounds__(512, 2)
rnn_v9(const void* latent, const void* ulat, const void* embd,
       const void* hidW, const void* hidb, const void* memW, const void* memb,
       const void* Wih, const void* Whh, const void* bih, const void* bhh,
       const void* catW, const void* catb, const void* outW, const void* outb,
       void* out, u32* ws) {
  // ---- LDS ----
  __shared__ __align__(16) char  stage[131072];    // 2 x 64 KB staging dbuf
  __shared__ __align__(16) char  arena[12288];     // phase-local scratch
  __shared__ __align__(16) float bhh_l[1536];      // 6144 B
  __shared__ __align__(16) float h_l[Hn];          // 2048 B, live 500 steps
  __shared__ float misc_l[2];                      // [0]=s0 [1]=inv_sum
  __shared__ int   s_tok;
  __shared__ u32   s_det;

  const int tid = threadIdx.x, blk = blockIdx.x;
  const int wv = tid >> 6, lane = tid & 63;
  const int gtid = blk * NT + tid;

  // ---- dtype detection: embed row PAD=1 is zero iff bf16 (verbatim) ----
  if (tid == 0) s_det = 0u;
  __syncthreads();
  if (tid < 256) {
    u32 v = ((const u32*)embd)[256 + tid];
    if (v) atomicOr(&s_det, 1u);
  }
  __syncthreads();
  const int mode = (s_det == 0u) ? 1 : 0;

  float* GEM = (float*)(ws + W_GEM);
  float* M2  = (float*)(ws + W_M2);
  float* cbF = (float*)(ws + W_CB);
  float* mWT = (float*)(ws + W_MWT);

  // ---- arena views (byte offsets; phases barrier-separated) ----
  float* ghq   = (float*)arena;            // GRU: [1536] dot+bhh      6144 B
  float* ps    = (float*)arena;            // attn: [128]              [0,512)
  float* ss    = (float*)(arena + 512);    // attn: [500]
  float* es    = (float*)(arena + 2560);   // attn: [500]
  float* Bpart = (float*)(arena + 4608);   // attn: [8][128]
  float* cuv   = (float*)(arena + 8704);   // attn: [128]
  float* ccs   = (float*)(arena + 4608);   // cc:  [512]
  float* lgs   = (float*)(arena + 6656);   // log: [16*34]

  // ======================= per-block private init ===========================
  for (int i = tid; i < 1536; i += NT) bhh_l[i] = ldv(bhh, i, mode);
  {  // h0 = latent @ hidW^T + hidb  (v4-exact order); tid covers 512 = Hn
    int k = tid;
    float a = ldv(hidb, k, mode);
    for (int q = 0; q < LDn; q++)
      a += ldv(latent, (size_t)blk * LDn + q, mode) * ldv(hidW, (size_t)k * LDn + q, mode);
    h_l[k] = a;
  }
  if (tid == 0) s_tok = 0;  // SOS

  // ======================= cooperative ws table build =======================
  if (gtid < 50688) {                                  // GEM = embed@Wih^T+bih
    int v = gtid / 1536, j = gtid - v * 1536;
    float a = ldv(bih, j, mode);
    for (int k = 0; k < Hn; k++)
      a += ldv(embd, (size_t)v * Hn + k, mode) * ldv(Wih, (size_t)j * Hn + k, mode);
    GEM[gtid] = a;
  }
  if (gtid < 65536) {                                  // M2[j][u] = catWr@memW
    int j = gtid >> 7, u = gtid & 127;
    float a = 0.f;
    for (int h = 0; h < Hn; h++)
      a += ldv(catW, (size_t)j * 1024 + 512 + h, mode) * ldv(memW, (size_t)h * UDn + u, mode);
    M2[(size_t)j * 128 + u] = a;
  }
  {                                                    // mWT[u][k] = memW[k][u]
    int u = gtid >> 9, k = gtid & 511;
    mWT[(size_t)u * 512 + k] = ldv(memW, (size_t)k * UDn + u, mode);
  }
  if (gtid < 512) {                                    // cbias
    int j = gtid;
    float a = ldv(catb, j, mode);
    for (int h = 0; h < Hn; h++)
      a += ldv(catW, (size_t)j * 1024 + 512 + h, mode) * ldv(memb, h, mode);
    cbF[j] = a;
  }
  __threadfence();
  __syncthreads();
  if (tid == 0) {  // poison-agnostic device barrier (proven pattern)
    if (blk == 0) {
      __hip_atomic_store(ws + W_INITC, 0u, __ATOMIC_RELAXED, __HIP_MEMORY_SCOPE_AGENT);
      astore(ws + W_SENT, SENT_V);
    }
    while (aload(ws + W_SENT) != SENT_V) __builtin_amdgcn_s_sleep(8);
    arrive(ws + W_INITC);
    waitGe(ws + W_INITC, NB);
  }
  __syncthreads();

  // ======================= 500 decode steps (no global sync) ================
  for (int t = 0; t < Tn; t++) {
    __syncthreads();  // s_tok + prev-step arena reads complete

    // ---- GRU: per-wave double-buffered global_load_lds pipeline (v8) ------
    {
      const int c = lane & 7;
      f4 xv[16];  // this lane's h chunk (c*64..c*64+64), loaded once per step
#pragma unroll
      for (int i = 0; i < 16; i++) xv[i] = *(const f4*)(h_l + c * 64 + i * 4);
      const int base = lane & 56;
      if (mode) {
        const u32 soff = (u32)((lane >> 3) * 128 + (((lane & 7) ^ (lane >> 3)) * 16));
        const char* W = (const char*)Whh;
        const int rp = lane >> 3;
#pragma unroll
        for (int r = 0; r < 8; r++)  // prologue: tile 0
          stage16(W + (size_t)(wv * 8 + r) * 1024 + soff,
                  stage + (size_t)(wv * 8 + r) * 1024);
        for (int tt = 0; tt < 24; tt++) {
          if (tt < 23) {
            char* nbuf = stage + (size_t)((tt + 1) & 1) * 65536;
#pragma unroll
            for (int r = 0; r < 8; r++)
              stage16(W + (size_t)((tt + 1) * 64 + wv * 8 + r) * 1024 + soff,
                      nbuf + (size_t)(wv * 8 + r) * 1024);
            asm volatile("s_waitcnt vmcnt(8)" ::: "memory");
          } else {
            asm volatile("s_waitcnt vmcnt(0)" ::: "memory");
          }
          const char* rb = stage + (size_t)(tt & 1) * 65536 +
                           (size_t)(wv * 8 + rp) * 1024 + c * 128;
          float a = 0.f;
#pragma unroll
          for (int s = 0; s < 8; s++) {  // v4/v5-exact chunk chain
            const u4 q = *(const u4*)(rb + ((s ^ c) * 16));
            const f4 xa = xv[s * 2], xb = xv[s * 2 + 1];
            a = fmaf(LO16(q.x), xa.x, fmaf(HI16(q.x), xa.y,
                fmaf(LO16(q.y), xa.z, fmaf(HI16(q.y), xa.w, a))));
            a = fmaf(LO16(q.z), xb.x, fmaf(HI16(q.z), xb.y,
                fmaf(LO16(q.w), xb.z, fmaf(HI16(q.w), xb.w, a))));
          }
          float sf = __shfl(a, base);  // in-order fold == v4's s += a_c
#pragma unroll
          for (int c2 = 1; c2 < 8; c2++) sf += __shfl(a, base + c2);
          if (c == 0) {
            const int d = tt * 64 + wv * 8 + rp;
            ghq[d] = sf + bhh_l[d];
          }
        }
      } else {
        // f32: 32-row tiles (64 KB), wave owns 4 rows, lanes<32 compute.
        const u32 l4 = (u32)(lane & 15);
        const u32 cs0 = (u32)(lane >> 4), cs1 = cs0 + 4;
        const u32 soff0 = cs0 * 256 + (((l4 & 8) | ((l4 ^ cs0) & 7))) * 16;
        const u32 soff1 = cs1 * 256 + (((l4 & 8) | ((l4 ^ cs1) & 7))) * 16;
        const char* W = (const char*)Whh;
        const int rp = lane >> 3, act = (lane < 32);
#pragma unroll
        for (int r = 0; r < 4; r++) {  // prologue: tile 0
          const char* src = W + (size_t)(wv * 4 + r) * 2048;
          char* dst = stage + (size_t)(wv * 4 + r) * 2048;
          stage16(src + soff0, dst);
          stage16(src + soff1, dst + 1024);
        }
        for (int tt = 0; tt < 48; tt++) {
          if (tt < 47) {
            char* nbuf = stage + (size_t)((tt + 1) & 1) * 65536;
#pragma unroll
            for (int r = 0; r < 4; r++) {
              const char* src = W + (size_t)((tt + 1) * 32 + wv * 4 + r) * 2048;
              char* dst = nbuf + (size_t)(wv * 4 + r) * 2048;
              stage16(src + soff0, dst);
              stage16(src + soff1, dst + 1024);
            }
            asm volatile("s_waitcnt vmcnt(8)" ::: "memory");
          } else {
            asm volatile("s_waitcnt vmcnt(0)" ::: "memory");
          }
          if (act) {
            const char* rb = stage + (size_t)(tt & 1) * 65536 +
                             (size_t)(wv * 4 + rp) * 2048 + c * 256;
            float a = 0.f;
#pragma unroll
            for (int i = 0; i < 16; i++) {  // v4-exact chunk chain (f32)
              const u32 j = (u32)((i & 8) | ((i ^ c) & 7));
              const f4 q = *(const f4*)(rb + j * 16);
              const f4 x = xv[i];
              a = fmaf(q.x, x.x, fmaf(q.y, x.y, fmaf(q.z, x.z, fmaf(q.w, x.w, a))));
            }
            float sf = __shfl(a, base);
#pragma unroll
            for (int c2 = 1; c2 < 8; c2++) sf += __shfl(a, base + c2);
            if (c == 0) {
              const int d = tt * 32 + wv * 4 + rp;
              ghq[d] = sf + bhh_l[d];
            }
          }
        }
      }
    }
    __syncthreads();

    // ---- gate nonlinearity + h update (verbatim v4 formulas) --------------
    float hnew;
    {
      const int j = tid;
      int tk = s_tok;
      if ((unsigned)tk > 32u) tk = 0;  // defensive clamp
      const float giR = GEM[tk * 1536 + j];
      const float giZ = GEM[tk * 1536 + 512 + j];
      const float giN = GEM[tk * 1536 + 1024 + j];
      const float rr = 1.f / (1.f + expf(-(giR + ghq[j])));
      const float zz = 1.f / (1.f + expf(-(giZ + ghq[512 + j])));
      const float nn = tanhf(giN + rr * ghq[1024 + j]);
      const float hv = h_l[j];
      hnew = (1.f - zz) * nn + zz * hv;
    }
    __syncthreads();
    h_l[tid] = hnew;
    __syncthreads();

    // ---- attention: p = mWT rows (transposed memW; v4-exact chain order) --
    {
      const int u = tid & 127, c8 = tid >> 7;  // chunks c8 and c8+4
      const f4* mw = (const f4*)(mWT + (size_t)u * 512);
      float aa = 0.f, ab = 0.f;
#pragma unroll
      for (int b = 0; b < 2; b++) {
        f4 qa[8], qb[8];
#pragma unroll
        for (int s = 0; s < 8; s++) qa[s] = mw[c8 * 16 + b * 8 + s];
#pragma unroll
        for (int s = 0; s < 8; s++) qb[s] = mw[(c8 + 4) * 16 + b * 8 + s];
#pragma unroll
        for (int s = 0; s < 8; s++) {
          const int k0 = c8 * 64 + b * 32 + s * 4;
          const f4 xa = *(const f4*)(h_l + k0);
          aa = fmaf(qa[s].x, xa.x, aa); aa = fmaf(qa[s].y, xa.y, aa);
          aa = fmaf(qa[s].z, xa.z, aa); aa = fmaf(qa[s].w, xa.w, aa);
          const int k1 = (c8 + 4) * 64 + b * 32 + s * 4;
          const f4 xb = *(const f4*)(h_l + k1);
          ab = fmaf(qb[s].x, xb.x, ab); ab = fmaf(qb[s].y, xb.y, ab);
          ab = fmaf(qb[s].z, xb.z, ab); ab = fmaf(qb[s].w, xb.w, ab);
        }
      }
      Bpart[c8 * UDn + u] = aa;
      Bpart[(c8 + 4) * UDn + u] = ab;
    }
    __syncthreads();
    if (tid < 128) {
      float s = 0.f;
#pragma unroll
      for (int c = 0; c < 8; c++) s += Bpart[c * UDn + tid];
      ps[tid] = s;
    } else if (tid < 192) {  // s0 = h_new . mem_b
      const int ln = tid - 128;
      float a = 0.f;
#pragma unroll
      for (int i = 0; i < 8; i++) { int k = ln + i * 64; a = fmaf(h_l[k], ldv(memb, k, mode), a); }
      for (int o = 32; o; o >>= 1) a += __shfl_down(a, o);
      if (ln == 0) misc_l[0] = a;
    }
    __syncthreads();

    // ---- scores[l] = p . ul[l] + s0 (batched loads, v4-exact order) -------
#pragma unroll
    for (int rep = 0; rep < 2; rep++) {
      const int l = (wv << 5) + (lane >> 1) + rep * 256, uh = lane & 1;
      float val = 0.f;
      if (l < Ln) {
        if (mode) {
          const u4* q4 = (const u4*)((const u32*)ulat +
                                     ((size_t)blk * Ln + l) * 64 + uh * 32);
          u4 Q[8];
#pragma unroll
          for (int s = 0; s < 8; s++) Q[s] = q4[s];
#pragma unroll
          for (int s = 0; s < 8; s++) {
#pragma unroll
            for (int e = 0; e < 4; e++) {
              const u32 d = Q[s][e];
              const int i = s * 4 + e;
              val = fmaf(bitsf(d << 16), ps[uh * 64 + i * 2], val);
              val = fmaf(bitsf(d & 0xffff0000u), ps[uh * 64 + i * 2 + 1], val);
            }
          }
        } else {
          const float* q = (const float*)ulat + ((size_t)blk * Ln + l) * UDn + uh * 64;
#pragma unroll 8
          for (int i = 0; i < 64; i++) val = fmaf(q[i], ps[uh * 64 + i], val);
        }
      }
      const float v2v = __shfl_down(val, 1);
      if ((lane & 1) == 0 && l < Ln) ss[l] = val + v2v + misc_l[0];
    }
    __syncthreads();
    if (wv == 0) {  // softmax stats over 500 (verbatim)
      float mx = -3.4e38f;
      for (int i = 0; i < 8; i++) {
        int l = lane + (i << 6);
        if (l < Ln) mx = fmaxf(mx, ss[l]);
      }
      for (int o = 32; o; o >>= 1) mx = fmaxf(mx, __shfl_xor(mx, o));
      float sum = 0.f;
      for (int i = 0; i < 8; i++) {
        int l = lane + (i << 6);
        if (l < Ln) { float e = expf(ss[l] - mx); es[l] = e; sum += e; }
      }
      for (int o = 32; o; o >>= 1) sum += __shfl_xor(sum, o);
      if (lane == 0) misc_l[1] = 1.f / sum;
    }
    __syncthreads();

    // ---- cu[u] = inv * sum_l es[l] * ul[l][u] (v8 verbatim) ---------------
    {
      const int u = tid & 127, lc = tid >> 7;  // lc in 0..3; also lc+4
      float aa = 0.f, ab = 0.f;
      if (mode) {
        const u16* q = (const u16*)ulat + ((size_t)blk * Ln) * UDn + u;
        const int e0 = (lc * 64 + 64 < Ln) ? lc * 64 + 64 : Ln;
#pragma unroll 8
        for (int l = lc * 64; l < e0; l++) aa = fmaf(es[l], b2f(q[(size_t)l * UDn]), aa);
        const int e1 = ((lc + 4) * 64 + 64 < Ln) ? (lc + 4) * 64 + 64 : Ln;
#pragma unroll 8
        for (int l = (lc + 4) * 64; l < e1; l++) ab = fmaf(es[l], b2f(q[(size_t)l * UDn]), ab);
      } else {
        const float* q = (const float*)ulat + ((size_t)blk * Ln) * UDn + u;
        const int e0 = (lc * 64 + 64 < Ln) ? lc * 64 + 64 : Ln;
#pragma unroll 8
        for (int l = lc * 64; l < e0; l++) aa = fmaf(es[l], q[(size_t)l * UDn], aa);
        const int e1 = ((lc + 4) * 64 + 64 < Ln) ? (lc + 4) * 64 + 64 : Ln;
#pragma unroll 8
        for (int l = (lc + 4) * 64; l < e1; l++) ab = fmaf(es[l], q[(size_t)l * UDn], ab);
      }
      Bpart[lc * UDn + u] = aa;
      Bpart[(lc + 4) * UDn + u] = ab;
    }
    __syncthreads();
    if (tid < 128) {
      float s = 0.f;
#pragma unroll
      for (int c = 0; c < 8; c++) s += Bpart[c * UDn + tid];
      cuv[tid] = s * misc_l[1];
    }
    __syncthreads();

    // ---- cc = tanh(catWl.h + M2.cu + cbias) -------------------------------
    if (mode) {
      // Pipelined: per tile, all waves stage 8 rows of tile tt+1 (row-XOR
      // swizzled source, linear LDS dest), counted vmcnt(8), raw barrier,
      // wave tt computes its 64 rows with v4's VERBATIM a0/a1 chain.
      const char* CW = (const char*)catW;  // row stride 2048 B (1024 u16)
#pragma unroll
      for (int r = 0; r < 8; r++) {  // prologue: tile 0
        const int row = wv * 8 + r;
        const u32 so = (u32)(((lane ^ row) & 63) << 4);
        stage16(CW + (size_t)row * 2048 + so, stage + (size_t)row * 1024);
      }
      for (int tt = 0; tt < 8; tt++) {
        if (tt < 7) {
          char* nbuf = stage + (size_t)((tt + 1) & 1) * 65536;
#pragma unroll
          for (int r = 0; r < 8; r++) {
            const int rl = wv * 8 + r, row = (tt + 1) * 64 + rl;
            const u32 so = (u32)(((lane ^ row) & 63) << 4);
            stage16(CW + (size_t)row * 2048 + so, nbuf + (size_t)rl * 1024);
          }
          asm volatile("s_waitcnt vmcnt(8)" ::: "memory");
        } else {
          asm volatile("s_waitcnt vmcnt(0)" ::: "memory");
        }
        __builtin_amdgcn_sched_barrier(0);
        __builtin_amdgcn_s_barrier();  // tile tt visible to all waves
        if (wv == tt) {
          const int j = tt * 64 + lane;
          const char* rb = stage + (size_t)(tt & 1) * 65536 + (size_t)lane * 1024;
          float a0 = 0.f, a1 = 0.f;
          for (int b2 = 0; b2 < 4; b2++) {
            u4 q0[8], q1[8];
#pragma unroll
            for (int s2 = 0; s2 < 8; s2++)
              q0[s2] = *(const u4*)(rb + ((((b2 * 8 + s2) ^ lane) & 63) << 4));
#pragma unroll
            for (int s2 = 0; s2 < 8; s2++)
              q1[s2] = *(const u4*)(rb + ((((32 + b2 * 8 + s2) ^ lane) & 63) << 4));
#pragma unroll
            for (int s2 = 0; s2 < 8; s2++) {
              const int e0 = b2 * 64 + s2 * 8;
              const f4 xa = *(const f4*)(h_l + e0), xb = *(const f4*)(h_l + e0 + 4);
              a0 = fmaf(LO16(q0[s2].x), xa.x, a0); a0 = fmaf(HI16(q0[s2].x), xa.y, a0);
              a0 = fmaf(LO16(q0[s2].y), xa.z, a0); a0 = fmaf(HI16(q0[s2].y), xa.w, a0);
              a0 = fmaf(LO16(q0[s2].z), xb.x, a0); a0 = fmaf(HI16(q0[s2].z), xb.y, a0);
              a0 = fmaf(LO16(q0[s2].w), xb.z, a0); a0 = fmaf(HI16(q0[s2].w), xb.w, a0);
              const int e1 = 256 + b2 * 64 + s2 * 8;
              const f4 ya = *(const f4*)(h_l + e1), yb = *(const f4*)(h_l + e1 + 4);
              a1 = fmaf(LO16(q1[s2].x), ya.x, a1); a1 = fmaf(HI16(q1[s2].x), ya.y, a1);
              a1 = fmaf(LO16(q1[s2].y), ya.z, a1); a1 = fmaf(HI16(q1[s2].y), ya.w, a1);
              a1 = fmaf(LO16(q1[s2].z), yb.x, a1); a1 = fmaf(HI16(q1[s2].z), yb.y, a1);
              a1 = fmaf(LO16(q1[s2].w), yb.z, a1); a1 = fmaf(HI16(q1[s2].w), yb.w, a1);
            }
          }
          {  // M2 part (f32, ascending per half — v4-exact, register chains)
            const f4* m2 = (const f4*)(M2 + (size_t)j * 128);
#pragma unroll
            for (int b2 = 0; b2 < 2; b2++) {
              f4 q0[8], q1[8];
#pragma unroll
              for (int s2 = 0; s2 < 8; s2++) q0[s2] = m2[b2 * 8 + s2];
#pragma unroll
              for (int s2 = 0; s2 < 8; s2++) q1[s2] = m2[16 + b2 * 8 + s2];
#pragma unroll
              for (int s2 = 0; s2 < 8; s2++) {
                const int e0 = b2 * 32 + s2 * 4;
                const f4 xc = *(const f4*)(cuv + e0);
                a0 = fmaf(q0[s2].x, xc.x, a0); a0 = fmaf(q0[s2].y, xc.y, a0);
                a0 = fmaf(q0[s2].z, xc.z, a0); a0 = fmaf(q0[s2].w, xc.w, a0);
                const int e1 = 64 + b2 * 32 + s2 * 4;
                const f4 yc = *(const f4*)(cuv + e1);
                a1 = fmaf(q1[s2].x, yc.x, a1); a1 = fmaf(q1[s2].y, yc.y, a1);
                a1 = fmaf(q1[s2].z, yc.z, a1); a1 = fmaf(q1[s2].w, yc.w, a1);
              }
            }
          }
          ccs[j] = tanhf(a0 + a1 + cbF[j]);
        }
        __builtin_amdgcn_s_barrier();  // compute done before buffer reuse
      }
      __syncthreads();  // full drain: ccs visible for logits
    } else {
      // mode0: v8's register-chain cc (verbatim)
      const int j = tid;
      float a0 = 0.f, a1 = 0.f;
      const f4* cw4 = (const f4*)catW + (size_t)j * 256;
      for (int b2 = 0; b2 < 8; b2++) {
        f4 q0[8], q1[8];
#pragma unroll
        for (int s2 = 0; s2 < 8; s2++) q0[s2] = cw4[b2 * 8 + s2];
#pragma unroll
        for (int s2 = 0; s2 < 8; s2++) q1[s2] = cw4[64 + b2 * 8 + s2];
#pragma unroll
        for (int s2 = 0; s2 < 8; s2++) {
          const int e0 = b2 * 32 + s2 * 4;
          const f4 xa = *(const f4*)(h_l + e0);
          a0 = fmaf(q0[s2].x, xa.x, a0); a0 = fmaf(q0[s2].y, xa.y, a0);
          a0 = fmaf(q0[s2].z, xa.z, a0); a0 = fmaf(q0[s2].w, xa.w, a0);
          const int e1 = 256 + b2 * 32 + s2 * 4;
          const f4 ya = *(const f4*)(h_l + e1);
          a1 = fmaf(q1[s2].x, ya.x, a1); a1 = fmaf(q1[s2].y, ya.y, a1);
          a1 = fmaf(q1[s2].z, ya.z, a1); a1 = fmaf(q1[s2].w, ya.w, a1);
        }
      }
      {  // M2 part
        const f4* m2 = (const f4*)(M2 + (size_t)j * 128);
#pragma unroll
        for (int b2 = 0; b2 < 2; b2++) {
          f4 q0[8], q1[8];
#pragma unroll
          for (int s2 = 0; s2 < 8; s2++) q0[s2] = m2[b2 * 8 + s2];
#pragma unroll
          for (int s2 = 0; s2 < 8; s2++) q1[s2] = m2[16 + b2 * 8 + s2];
#pragma unroll
          for (int s2 = 0; s2 < 8; s2++) {
            const int e0 = b2 * 32 + s2 * 4;
            const f4 xc = *(const f4*)(cuv + e0);
            a0 = fmaf(q0[s2].x, xc.x, a0); a0 = fmaf(q0[s2].y, xc.y, a0);
            a0 = fmaf(q0[s2].z, xc.z, a0); a0 = fmaf(q0[s2].w, xc.w, a0);
            const int e1 = 64 + b2 * 32 + s2 * 4;
            const f4 yc = *(const f4*)(cuv + e1);
            a1 = fmaf(q1[s2].x, yc.x, a1); a1 = fmaf(q1[s2].y, yc.y, a1);
            a1 = fmaf(q1[s2].z, yc.z, a1); a1 = fmaf(q1[s2].w, yc.w, a1);
          }
        }
      }
      ccs[j] = tanhf(a0 + a1 + cbF[j]);
      __syncthreads();
    }

    // ---- logits + argmax + output (verbatim chains; 2 j0 per wave) --------
#pragma unroll
    for (int rep = 0; rep < 2; rep++) {
      if (lane < Vn) {
        const int w2i = wv + rep * 8;
        const int j0 = w2i << 5;
        float part = 0.f;
#pragma unroll
        for (int q = 0; q < 32; q++)
          part = fmaf(ccs[j0 + q], ldv(outW, (size_t)lane * Hn + j0 + q, mode), part);
        lgs[w2i * 34 + lane] = part;
      }
    }
    __syncthreads();
    if (wv == 0) {
      float lg = -3.4e38f;
      int idx = 0;
      if (lane < Vn) {
        float s = ldv(outb, lane, mode);
#pragma unroll
        for (int w2 = 0; w2 < 16; w2++) s += lgs[w2 * 34 + lane];
        if (mode) ((u16*)out)[(size_t)blk * (Vn * Ln) + lane * Ln + t] = f2b(s);
        else ((float*)out)[(size_t)blk * (Vn * Ln) + lane * Ln + t] = s;
        lg = s;
        idx = lane;
      }
      for (int o = 32; o; o >>= 1) {  // np argmax: first max wins
        const float ov = __shfl_down(lg, o);
        const int oi = __shfl_down(idx, o);
        if (ov > lg || (ov == lg && oi < idx)) { lg = ov; idx = oi; }
      }
      if (lane == 0) s_tok = idx;
    }
  }
}

extern "C" void kernel_launch(void* const* d_in, const int* in_sizes, int n_in,
                              void* d_out, int out_size, void* d_ws, size_t ws_size,
                              hipStream_t stream) {
  (void)in_sizes; (void)n_in; (void)out_size;
  if (ws_size < (size_t)W_END * 4) return;  // needs ~0.73 MB scratch
  hipLaunchKernelGGL(rnn_v9, dim3(NB), dim3(NT), 0, stream,
                     d_in[0],   // latent
                     d_in[1],   // upsampled_latent
                     d_in[3],   // embed (d_in[2]=target unused in eval)
                     d_in[4],   // hid_W
                     d_in[5],   // hid_b
                     d_in[6],   // mem_W
                     d_in[7],   // mem_b
                     d_in[8],   // W_ih
                     d_in[9],   // W_hh
                     d_in[10],  // b_ih
                     d_in[11],  // b_hh
                     d_in[12],  // cat_W
                     d_in[13],  // cat_b
                     d_in[14],  // out_W
                     d_in[15],  // out_b
                     d_out, (u32*)d_ws);
}

// Round 9
// 62603.418 us; speedup vs baseline: 1.6177x; 1.2371x over previous
//
#include <hip/hip_runtime.h>
#include <hip/hip_bf16.h>
#include <math.h>

// ============================================================================
// RNNDecoder v11: v10 (2 blocks per row: j-split GRU+cc, A owns attention/
// logits, B overlaps cc catW-part under A's attention) with the WORKSPACE
// LAYOUT FIXED for 128 pairs (v10 sized exchange regions for 64 pairs; pairs
// >=64 stomped GEM/CUX/CCX -> absmax 2.24). All compute chains and the
// exchange protocol are byte-identical to v10 (= verbatim v4-v9 chains).
// ============================================================================

typedef unsigned short u16;
typedef unsigned int u32;
typedef float f4 __attribute__((ext_vector_type(4)));
typedef u32 u4 __attribute__((ext_vector_type(4)));

#define NB 256
#define NT 512
#define Ln 500
#define Hn 512
#define LDn 256
#define UDn 128
#define Vn 33
#define Tn 500
#define SENT_V 0x9E3779B1u

// ---- workspace u32 offsets (128 pairs) ----
#define W_INITC 0u
#define W_SENT  1u
#define W_FLG   64u        // [128 pair][8 kind][8 pad]; 0=hA 1=hB 2=cu 3=ccB 4=tok
#define W_HX    8256u      // f32 [128][512] h exchange
#define W_CUX   73792u     // f32 [128][128]
#define W_CCX   90176u     // f32 [128][512] (B writes [128,512))
#define W_TOKX  155712u    // int [128][8]
#define W_GEM   156736u    // f32 [33][1536]
#define W_M2    207424u    // f32 [512][128]
#define W_CB    272960u    // f32 [512]
#define W_MWT   273472u    // f32 [128][512] memW^T
#define W_END   339008u    // ~1.36 MB

__device__ __forceinline__ float b2f(u16 v) {
  u32 x = ((u32)v) << 16; float f; __builtin_memcpy(&f, &x, 4); return f;
}
__device__ __forceinline__ float bitsf(u32 x) {
  float f; __builtin_memcpy(&f, &x, 4); return f;
}
#define LO16(d) bitsf((u32)(d) << 16)
#define HI16(d) bitsf((u32)(d) & 0xffff0000u)
__device__ __forceinline__ u16 f2b(float f) {  // RNE
  u32 x; __builtin_memcpy(&x, &f, 4);
  x += 0x7fffu + ((x >> 16) & 1u);
  return (u16)(x >> 16);
}
__device__ __forceinline__ float ldv(const void* p, size_t i, int mode) {
  return mode ? b2f(((const u16*)p)[i]) : ((const float*)p)[i];
}
__device__ __forceinline__ u32 aload(u32* p) {
  return __hip_atomic_load(p, __ATOMIC_ACQUIRE, __HIP_MEMORY_SCOPE_AGENT);
}
__device__ __forceinline__ void waitGe(u32* p, u32 tgt) {
  while (aload(p) < tgt) __builtin_amdgcn_s_sleep(4);
}
__device__ __forceinline__ void arrive(u32* p) {  // release RMW (proven v2/v3)
  __hip_atomic_fetch_add(p, 1u, __ATOMIC_RELEASE, __HIP_MEMORY_SCOPE_AGENT);
}
__device__ __forceinline__ void astore(u32* p, u32 v) {
  __hip_atomic_store(p, v, __ATOMIC_RELEASE, __HIP_MEMORY_SCOPE_AGENT);
}
__device__ __forceinline__ void pace_zero(u32* p) {
  __hip_atomic_store(p, 0u, __ATOMIC_RELAXED, __HIP_MEMORY_SCOPE_AGENT);
}
// relaxed fast-poll + single acquire on success (no per-poll buffer_inv)
__device__ __forceinline__ void fpoll(u32* p, u32 tgt) {
  int sp = 0;
  for (;;) {
    if (__hip_atomic_load(p, __ATOMIC_RELAXED, __HIP_MEMORY_SCOPE_AGENT) >= tgt) break;
    if (++sp >= 4096) { sp = 0; if (aload(p) >= tgt) return; }
    __builtin_amdgcn_s_sleep(2);
  }
  (void)aload(p);  // acquire edge: subsequent plain loads see published data
}
__device__ __forceinline__ void stage16(const void* g, void* l) {
  __builtin_amdgcn_global_load_lds(
      (const __attribute__((address_space(1))) u32*)g,
      (__attribute__((address_space(3))) u32*)l, 16, 0, 0);
}

extern "C" __global__ void __launch_bounds__(512, 2)
rnn_v11(const void* latent, const void* ulat, const void* embd,
        const void* hidW, const void* hidb, const void* memW, const void* memb,
        const void* Wih, const void* Whh, const void* bih, const void* bhh,
        const void* catW, const void* catb, const void* outW, const void* outb,
        void* out, u32* ws) {
  __shared__ __align__(16) char  stage[131072];
  __shared__ __align__(16) char  arena[12288];
  __shared__ __align__(16) float bhh_l[1536];
  __shared__ __align__(16) float h_l[Hn];
  __shared__ float misc_l[2];
  __shared__ int   s_tok;
  __shared__ u32   s_det;

  const int tid = threadIdx.x, blk = blockIdx.x;
  const int wv = tid >> 6, lane = tid & 63;
  const int pr = blk >> 1, role = blk & 1;   // pair row (0..127), A=0/B=1
  const int gtid = blk * NT + tid;

  if (tid == 0) s_det = 0u;
  __syncthreads();
  if (tid < 256) {
    u32 v = ((const u32*)embd)[256 + tid];
    if (v) atomicOr(&s_det, 1u);
  }
  __syncthreads();
  const int mode = (s_det == 0u) ? 1 : 0;

  float* GEM = (float*)(ws + W_GEM);
  float* M2  = (float*)(ws + W_M2);
  float* cbF = (float*)(ws + W_CB);
  float* mWT = (float*)(ws + W_MWT);
  float* HX  = (float*)(ws + W_HX) + (size_t)pr * 512;
  float* CUX = (float*)(ws + W_CUX) + (size_t)pr * 128;
  float* CCX = (float*)(ws + W_CCX) + (size_t)pr * 512;
  int*   TKX = (int*)(ws + W_TOKX) + (size_t)pr * 8;
  u32*   FLG = ws + W_FLG + (u32)pr * 64u;   // + kind*8

  float* ghq   = (float*)arena;            // GRU: [768] local rows
  float* pa    = (float*)arena;            // B cc: [384][2] partials (post-gates)
  float* ps    = (float*)arena;            // A attn
  float* ss    = (float*)(arena + 512);
  float* es    = (float*)(arena + 2560);
  float* Bpart = (float*)(arena + 4608);
  float* cuv   = (float*)(arena + 8704);
  float* ccs   = (float*)(arena + 4608);   // A: [512] cc gather
  float* lgs   = (float*)(arena + 6656);

  // ======================= per-block init ===================================
  for (int i = tid; i < 1536; i += NT) bhh_l[i] = ldv(bhh, i, mode);
  {  // full h0 (verbatim chain), computed redundantly by both pair members
    int k = tid;
    float a = ldv(hidb, k, mode);
    for (int q = 0; q < LDn; q++)
      a += ldv(latent, (size_t)pr * LDn + q, mode) * ldv(hidW, (size_t)k * LDn + q, mode);
    h_l[k] = a;
  }
  if (tid == 0) s_tok = 0;

  // ======================= cooperative ws build =============================
  if (gtid < 8192) pace_zero(ws + W_FLG + gtid);       // flags zero (128 pairs)
  if (gtid < 50688) {
    int v = gtid / 1536, j = gtid - v * 1536;
    float a = ldv(bih, j, mode);
    for (int k = 0; k < Hn; k++)
      a += ldv(embd, (size_t)v * Hn + k, mode) * ldv(Wih, (size_t)j * Hn + k, mode);
    GEM[gtid] = a;
  }
  if (gtid < 65536) {
    int j = gtid >> 7, u = gtid & 127;
    float a = 0.f;
    for (int h = 0; h < Hn; h++)
      a += ldv(catW, (size_t)j * 1024 + 512 + h, mode) * ldv(memW, (size_t)h * UDn + u, mode);
    M2[(size_t)j * 128 + u] = a;
  }
  if (gtid < 65536) {
    int u = gtid >> 9, k = gtid & 511;
    mWT[(size_t)u * 512 + k] = ldv(memW, (size_t)k * UDn + u, mode);
  }
  if (gtid < 512) {
    int j = gtid;
    float a = ldv(catb, j, mode);
    for (int h = 0; h < Hn; h++)
      a += ldv(catW, (size_t)j * 1024 + 512 + h, mode) * ldv(memb, h, mode);
    cbF[j] = a;
  }
  __threadfence();
  __syncthreads();
  if (tid == 0) {  // poison-agnostic device barrier
    if (blk == 0) {
      __hip_atomic_store(ws + W_INITC, 0u, __ATOMIC_RELAXED, __HIP_MEMORY_SCOPE_AGENT);
      astore(ws + W_SENT, SENT_V);
    }
    while (aload(ws + W_SENT) != SENT_V) __builtin_amdgcn_s_sleep(8);
    arrive(ws + W_INITC);
    waitGe(ws + W_INITC, NB);
  }
  __syncthreads();

  const int roff = role * 256;  // this block's j-offset

  // ======================= 500 decode steps =================================
  for (int t = 0; t < Tn; t++) {
    __syncthreads();

    // ---- GRU: 768 rows (this half), v9 ring pipeline, chains verbatim -----
    {
      const int c = lane & 7;
      f4 xv[16];
#pragma unroll
      for (int i = 0; i < 16; i++) xv[i] = *(const f4*)(h_l + c * 64 + i * 4);
      const int base = lane & 56;
      if (mode) {
        const u32 soff = (u32)((lane >> 3) * 128 + (((lane & 7) ^ (lane >> 3)) * 16));
        const char* W = (const char*)Whh;
        const int rp = lane >> 3;
#pragma unroll
        for (int r = 0; r < 8; r++) {
          const int ri = wv * 8 + r;
          const int wrow = (ri >> 8) * 512 + roff + (ri & 255);
          stage16(W + (size_t)wrow * 1024 + soff, stage + (size_t)ri * 1024);
        }
        for (int tt = 0; tt < 12; tt++) {
          if (tt < 11) {
            char* nbuf = stage + (size_t)((tt + 1) & 1) * 65536;
#pragma unroll
            for (int r = 0; r < 8; r++) {
              const int rl = wv * 8 + r, ri = (tt + 1) * 64 + rl;
              const int wrow = (ri >> 8) * 512 + roff + (ri & 255);
              stage16(W + (size_t)wrow * 1024 + soff, nbuf + (size_t)rl * 1024);
            }
            asm volatile("s_waitcnt vmcnt(8)" ::: "memory");
          } else {
            asm volatile("s_waitcnt vmcnt(0)" ::: "memory");
          }
          const char* rb = stage + (size_t)(tt & 1) * 65536 +
                           (size_t)(wv * 8 + rp) * 1024 + c * 128;
          float a = 0.f;
#pragma unroll
          for (int s = 0; s < 8; s++) {
            const u4 q = *(const u4*)(rb + ((s ^ c) * 16));
            const f4 xa = xv[s * 2], xb = xv[s * 2 + 1];
            a = fmaf(LO16(q.x), xa.x, fmaf(HI16(q.x), xa.y,
                fmaf(LO16(q.y), xa.z, fmaf(HI16(q.y), xa.w, a))));
            a = fmaf(LO16(q.z), xb.x, fmaf(HI16(q.z), xb.y,
                fmaf(LO16(q.w), xb.z, fmaf(HI16(q.w), xb.w, a))));
          }
          float sf = __shfl(a, base);
#pragma unroll
          for (int c2 = 1; c2 < 8; c2++) sf += __shfl(a, base + c2);
          if (c == 0) {
            const int ri = tt * 64 + wv * 8 + rp;
            const int wrow = (ri >> 8) * 512 + roff + (ri & 255);
            ghq[ri] = sf + bhh_l[wrow];
          }
        }
      } else {
        const u32 l4 = (u32)(lane & 15);
        const u32 cs0 = (u32)(lane >> 4), cs1 = cs0 + 4;
        const u32 soff0 = cs0 * 256 + (((l4 & 8) | ((l4 ^ cs0) & 7))) * 16;
        const u32 soff1 = cs1 * 256 + (((l4 & 8) | ((l4 ^ cs1) & 7))) * 16;
        const char* W = (const char*)Whh;
        const int rp = lane >> 3, act = (lane < 32);
#pragma unroll
        for (int r = 0; r < 4; r++) {
          const int ri = wv * 4 + r;
          const int wrow = (ri >> 8) * 512 + roff + (ri & 255);
          const char* src = W + (size_t)wrow * 2048;
          char* dst = stage + (size_t)ri * 2048;
          stage16(src + soff0, dst);
          stage16(src + soff1, dst + 1024);
        }
        for (int tt = 0; tt < 24; tt++) {
          if (tt < 23) {
            char* nbuf = stage + (size_t)((tt + 1) & 1) * 65536;
#pragma unroll
            for (int r = 0; r < 4; r++) {
              const int rl = wv * 4 + r, ri = (tt + 1) * 32 + rl;
              const int wrow = (ri >> 8) * 512 + roff + (ri & 255);
              const char* src = W + (size_t)wrow * 2048;
              char* dst = nbuf + (size_t)rl * 2048;
              stage16(src + soff0, dst);
              stage16(src + soff1, dst + 1024);
            }
            asm volatile("s_waitcnt vmcnt(8)" ::: "memory");
          } else {
            asm volatile("s_waitcnt vmcnt(0)" ::: "memory");
          }
          if (act) {
            const char* rb = stage + (size_t)(tt & 1) * 65536 +
                             (size_t)(wv * 4 + rp) * 2048 + c * 256;
            float a = 0.f;
#pragma unroll
            for (int i = 0; i < 16; i++) {
              const u32 j = (u32)((i & 8) | ((i ^ c) & 7));
              const f4 q = *(const f4*)(rb + j * 16);
              const f4 x = xv[i];
              a = fmaf(q.x, x.x, fmaf(q.y, x.y, fmaf(q.z, x.z, fmaf(q.w, x.w, a))));
            }
            float sf = __shfl(a, base);
#pragma unroll
            for (int c2 = 1; c2 < 8; c2++) sf += __shfl(a, base + c2);
            if (c == 0) {
              const int ri = tt * 32 + wv * 4 + rp;
              const int wrow = (ri >> 8) * 512 + roff + (ri & 255);
              ghq[ri] = sf + bhh_l[wrow];
            }
          }
        }
      }
    }
    __syncthreads();

    // ---- gates (256 own rows; verbatim formulas) + publish h half ---------
    if (tid < 256) {
      const int jl = tid, jg = roff + jl;
      int tk = s_tok;
      if ((unsigned)tk > 32u) tk = 0;
      const float giR = GEM[tk * 1536 + jg];
      const float giZ = GEM[tk * 1536 + 512 + jg];
      const float giN = GEM[tk * 1536 + 1024 + jg];
      const float rr = 1.f / (1.f + expf(-(giR + ghq[jl])));
      const float zz = 1.f / (1.f + expf(-(giZ + ghq[256 + jl])));
      const float nn = tanhf(giN + rr * ghq[512 + jl]);
      const float hv = h_l[jg];
      const float hnew = (1.f - zz) * nn + zz * hv;
      h_l[jg] = hnew;
      HX[jg] = hnew;                      // plain store (flushed by release)
    }
    __syncthreads();                      // drains vmcnt for all waves
    if (tid == 0) arrive(FLG + role * 8); // kind 0/1: my h half ready
    if (tid == 0) fpoll(FLG + (1 - role) * 8, (u32)(t + 1));
    __syncthreads();
    if (tid < 256) {                      // read partner's h half
      const int jo = (1 - role) * 256 + tid;
      h_l[jo] = HX[jo];
    }
    __syncthreads();

    if (role == 0) {
      // =========== A: attention (verbatim v9) → publish cu ================
      {
        const int u = tid & 127, c8 = tid >> 7;
        const f4* mw = (const f4*)(mWT + (size_t)u * 512);
        float aa = 0.f, ab = 0.f;
#pragma unroll
        for (int b = 0; b < 2; b++) {
          f4 qa[8], qb[8];
#pragma unroll
          for (int s = 0; s < 8; s++) qa[s] = mw[c8 * 16 + b * 8 + s];
#pragma unroll
          for (int s = 0; s < 8; s++) qb[s] = mw[(c8 + 4) * 16 + b * 8 + s];
#pragma unroll
          for (int s = 0; s < 8; s++) {
            const int k0 = c8 * 64 + b * 32 + s * 4;
            const f4 xa = *(const f4*)(h_l + k0);
            aa = fmaf(qa[s].x, xa.x, aa); aa = fmaf(qa[s].y, xa.y, aa);
            aa = fmaf(qa[s].z, xa.z, aa); aa = fmaf(qa[s].w, xa.w, aa);
            const int k1 = (c8 + 4) * 64 + b * 32 + s * 4;
            const f4 xb = *(const f4*)(h_l + k1);
            ab = fmaf(qb[s].x, xb.x, ab); ab = fmaf(qb[s].y, xb.y, ab);
            ab = fmaf(qb[s].z, xb.z, ab); ab = fmaf(qb[s].w, xb.w, ab);
          }
        }
        Bpart[c8 * UDn + u] = aa;
        Bpart[(c8 + 4) * UDn + u] = ab;
      }
      __syncthreads();
      if (tid < 128) {
        float s = 0.f;
#pragma unroll
        for (int c = 0; c < 8; c++) s += Bpart[c * UDn + tid];
        ps[tid] = s;
      } else if (tid < 192) {
        const int ln = tid - 128;
        float a = 0.f;
#pragma unroll
        for (int i = 0; i < 8; i++) { int k = ln + i * 64; a = fmaf(h_l[k], ldv(memb, k, mode), a); }
        for (int o = 32; o; o >>= 1) a += __shfl_down(a, o);
        if (ln == 0) misc_l[0] = a;
      }
      __syncthreads();
#pragma unroll
      for (int rep = 0; rep < 2; rep++) {
        const int l = (wv << 5) + (lane >> 1) + rep * 256, uh = lane & 1;
        float val = 0.f;
        if (l < Ln) {
          if (mode) {
            const u4* q4 = (const u4*)((const u32*)ulat +
                                       ((size_t)pr * Ln + l) * 64 + uh * 32);
            u4 Q[8];
#pragma unroll
            for (int s = 0; s < 8; s++) Q[s] = q4[s];
#pragma unroll
            for (int s = 0; s < 8; s++) {
#pragma unroll
              for (int e = 0; e < 4; e++) {
                const u32 d = Q[s][e];
                const int i = s * 4 + e;
                val = fmaf(bitsf(d << 16), ps[uh * 64 + i * 2], val);
                val = fmaf(bitsf(d & 0xffff0000u), ps[uh * 64 + i * 2 + 1], val);
              }
            }
          } else {
            const float* q = (const float*)ulat + ((size_t)pr * Ln + l) * UDn + uh * 64;
#pragma unroll 8
            for (int i = 0; i < 64; i++) val = fmaf(q[i], ps[uh * 64 + i], val);
          }
        }
        const float v2v = __shfl_down(val, 1);
        if ((lane & 1) == 0 && l < Ln) ss[l] = val + v2v + misc_l[0];
      }
      __syncthreads();
      if (wv == 0) {
        float mx = -3.4e38f;
        for (int i = 0; i < 8; i++) {
          int l = lane + (i << 6);
          if (l < Ln) mx = fmaxf(mx, ss[l]);
        }
        for (int o = 32; o; o >>= 1) mx = fmaxf(mx, __shfl_xor(mx, o));
        float sum = 0.f;
        for (int i = 0; i < 8; i++) {
          int l = lane + (i << 6);
          if (l < Ln) { float e = expf(ss[l] - mx); es[l] = e; sum += e; }
        }
        for (int o = 32; o; o >>= 1) sum += __shfl_xor(sum, o);
        if (lane == 0) misc_l[1] = 1.f / sum;
      }
      __syncthreads();
      {
        const int u = tid & 127, lc = tid >> 7;
        float aa = 0.f, ab = 0.f;
        if (mode) {
          const u16* q = (const u16*)ulat + ((size_t)pr * Ln) * UDn + u;
          const int e0 = (lc * 64 + 64 < Ln) ? lc * 64 + 64 : Ln;
#pragma unroll 8
          for (int l = lc * 64; l < e0; l++) aa = fmaf(es[l], b2f(q[(size_t)l * UDn]), aa);
          const int e1 = ((lc + 4) * 64 + 64 < Ln) ? (lc + 4) * 64 + 64 : Ln;
#pragma unroll 8
          for (int l = (lc + 4) * 64; l < e1; l++) ab = fmaf(es[l], b2f(q[(size_t)l * UDn]), ab);
        } else {
          const float* q = (const float*)ulat + ((size_t)pr * Ln) * UDn + u;
          const int e0 = (lc * 64 + 64 < Ln) ? lc * 64 + 64 : Ln;
#pragma unroll 8
          for (int l = lc * 64; l < e0; l++) aa = fmaf(es[l], q[(size_t)l * UDn], aa);
          const int e1 = ((lc + 4) * 64 + 64 < Ln) ? (lc + 4) * 64 + 64 : Ln;
#pragma unroll 8
          for (int l = (lc + 4) * 64; l < e1; l++) ab = fmaf(es[l], q[(size_t)l * UDn], ab);
        }
        Bpart[lc * UDn + u] = aa;
        Bpart[(lc + 4) * UDn + u] = ab;
      }
      __syncthreads();
      if (tid < 128) {
        float s = 0.f;
#pragma unroll
        for (int c = 0; c < 8; c++) s += Bpart[c * UDn + tid];
        const float cv = s * misc_l[1];
        cuv[tid] = cv;
        CUX[tid] = cv;                    // plain store
      }
      __syncthreads();                    // vmcnt drain
      if (tid == 0) arrive(FLG + 2 * 8);  // kind2: cu ready

      // ---- A's cc rows j in [0,128): v8 register chains (verbatim) --------
      if (tid < 128) {
        const int j = tid;
        float a0 = 0.f, a1 = 0.f;
        if (mode) {
          const u4* cw = (const u4*)((const u16*)catW + (size_t)j * 1024);
          for (int b2 = 0; b2 < 4; b2++) {
            u4 q0[8], q1[8];
#pragma unroll
            for (int s2 = 0; s2 < 8; s2++) q0[s2] = cw[b2 * 8 + s2];
#pragma unroll
            for (int s2 = 0; s2 < 8; s2++) q1[s2] = cw[32 + b2 * 8 + s2];
#pragma unroll
            for (int s2 = 0; s2 < 8; s2++) {
              const int e0 = b2 * 64 + s2 * 8;
              const f4 xa = *(const f4*)(h_l + e0), xb = *(const f4*)(h_l + e0 + 4);
              a0 = fmaf(LO16(q0[s2].x), xa.x, a0); a0 = fmaf(HI16(q0[s2].x), xa.y, a0);
              a0 = fmaf(LO16(q0[s2].y), xa.z, a0); a0 = fmaf(HI16(q0[s2].y), xa.w, a0);
              a0 = fmaf(LO16(q0[s2].z), xb.x, a0); a0 = fmaf(HI16(q0[s2].z), xb.y, a0);
              a0 = fmaf(LO16(q0[s2].w), xb.z, a0); a0 = fmaf(HI16(q0[s2].w), xb.w, a0);
              const int e1 = 256 + b2 * 64 + s2 * 8;
              const f4 ya = *(const f4*)(h_l + e1), yb = *(const f4*)(h_l + e1 + 4);
              a1 = fmaf(LO16(q1[s2].x), ya.x, a1); a1 = fmaf(HI16(q1[s2].x), ya.y, a1);
              a1 = fmaf(LO16(q1[s2].y), ya.z, a1); a1 = fmaf(HI16(q1[s2].y), ya.w, a1);
              a1 = fmaf(LO16(q1[s2].z), yb.x, a1); a1 = fmaf(HI16(q1[s2].z), yb.y, a1);
              a1 = fmaf(LO16(q1[s2].w), yb.z, a1); a1 = fmaf(HI16(q1[s2].w), yb.w, a1);
            }
          }
        } else {
          const f4* cw4 = (const f4*)catW + (size_t)j * 256;
          for (int b2 = 0; b2 < 8; b2++) {
            f4 q0[8], q1[8];
#pragma unroll
            for (int s2 = 0; s2 < 8; s2++) q0[s2] = cw4[b2 * 8 + s2];
#pragma unroll
            for (int s2 = 0; s2 < 8; s2++) q1[s2] = cw4[64 + b2 * 8 + s2];
#pragma unroll
            for (int s2 = 0; s2 < 8; s2++) {
              const int e0 = b2 * 32 + s2 * 4;
              const f4 xa = *(const f4*)(h_l + e0);
              a0 = fmaf(q0[s2].x, xa.x, a0); a0 = fmaf(q0[s2].y, xa.y, a0);
              a0 = fmaf(q0[s2].z, xa.z, a0); a0 = fmaf(q0[s2].w, xa.w, a0);
              const int e1 = 256 + b2 * 32 + s2 * 4;
              const f4 ya = *(const f4*)(h_l + e1);
              a1 = fmaf(q1[s2].x, ya.x, a1); a1 = fmaf(q1[s2].y, ya.y, a1);
              a1 = fmaf(q1[s2].z, ya.z, a1); a1 = fmaf(q1[s2].w, ya.w, a1);
            }
          }
        }
        {
          const f4* m2 = (const f4*)(M2 + (size_t)j * 128);
#pragma unroll
          for (int b2 = 0; b2 < 2; b2++) {
            f4 q0[8], q1[8];
#pragma unroll
            for (int s2 = 0; s2 < 8; s2++) q0[s2] = m2[b2 * 8 + s2];
#pragma unroll
            for (int s2 = 0; s2 < 8; s2++) q1[s2] = m2[16 + b2 * 8 + s2];
#pragma unroll
            for (int s2 = 0; s2 < 8; s2++) {
              const int e0 = b2 * 32 + s2 * 4;
              const f4 xc = *(const f4*)(cuv + e0);
              a0 = fmaf(q0[s2].x, xc.x, a0); a0 = fmaf(q0[s2].y, xc.y, a0);
              a0 = fmaf(q0[s2].z, xc.z, a0); a0 = fmaf(q0[s2].w, xc.w, a0);
              const int e1 = 64 + b2 * 32 + s2 * 4;
              const f4 yc = *(const f4*)(cuv + e1);
              a1 = fmaf(q1[s2].x, yc.x, a1); a1 = fmaf(q1[s2].y, yc.y, a1);
              a1 = fmaf(q1[s2].z, yc.z, a1); a1 = fmaf(q1[s2].w, yc.w, a1);
            }
          }
        }
        ccs[j] = tanhf(a0 + a1 + cbF[j]);
      }
      if (tid == 0) fpoll(FLG + 3 * 8, (u32)(t + 1));  // ccB ready
      __syncthreads();
      if (tid >= 128) ccs[tid] = CCX[tid];  // gather B's 384 cc values
      __syncthreads();

      // ---- logits + argmax + output (verbatim) ----------------------------
#pragma unroll
      for (int rep = 0; rep < 2; rep++) {
        if (lane < Vn) {
          const int w2i = wv + rep * 8;
          const int j0 = w2i << 5;
          float part = 0.f;
#pragma unroll
          for (int q = 0; q < 32; q++)
            part = fmaf(ccs[j0 + q], ldv(outW, (size_t)lane * Hn + j0 + q, mode), part);
          lgs[w2i * 34 + lane] = part;
        }
      }
      __syncthreads();
      if (wv == 0) {
        float lg = -3.4e38f;
        int idx = 0;
        if (lane < Vn) {
          float s = ldv(outb, lane, mode);
#pragma unroll
          for (int w2 = 0; w2 < 16; w2++) s += lgs[w2 * 34 + lane];
          if (mode) ((u16*)out)[(size_t)pr * (Vn * Ln) + lane * Ln + t] = f2b(s);
          else ((float*)out)[(size_t)pr * (Vn * Ln) + lane * Ln + t] = s;
          lg = s;
          idx = lane;
        }
        for (int o = 32; o; o >>= 1) {
          const float ov = __shfl_down(lg, o);
          const int oi = __shfl_down(idx, o);
          if (ov > lg || (ov == lg && oi < idx)) { lg = ov; idx = oi; }
        }
        if (lane == 0) { s_tok = idx; TKX[0] = idx; }
        asm volatile("s_waitcnt vmcnt(0)" ::: "memory");
        if (lane == 0) arrive(FLG + 4 * 8);  // kind4: token ready
      }
    } else {
      // =========== B: cc catW-part (h-only) overlapped, then finish =======
      if (mode) {
        const char* CW = (const char*)catW;
#pragma unroll
        for (int r = 0; r < 8; r++) {
          const int rl = wv * 8 + r, row = 128 + rl;
          const u32 so = (u32)(((lane ^ row) & 63) << 4);
          stage16(CW + (size_t)row * 2048 + so, stage + (size_t)rl * 1024);
        }
        for (int tt = 0; tt < 6; tt++) {
          if (tt < 5) {
            char* nbuf = stage + (size_t)((tt + 1) & 1) * 65536;
#pragma unroll
            for (int r = 0; r < 8; r++) {
              const int rl = wv * 8 + r, row = 128 + (tt + 1) * 64 + rl;
              const u32 so = (u32)(((lane ^ row) & 63) << 4);
              stage16(CW + (size_t)row * 2048 + so, nbuf + (size_t)rl * 1024);
            }
            asm volatile("s_waitcnt vmcnt(8)" ::: "memory");
          } else {
            asm volatile("s_waitcnt vmcnt(0)" ::: "memory");
          }
          __builtin_amdgcn_sched_barrier(0);
          __builtin_amdgcn_s_barrier();
          if (wv == tt) {
            const char* rb = stage + (size_t)(tt & 1) * 65536 + (size_t)lane * 1024;
            float a0 = 0.f, a1 = 0.f;
            for (int b2 = 0; b2 < 4; b2++) {
              u4 q0[8], q1[8];
#pragma unroll
              for (int s2 = 0; s2 < 8; s2++)
                q0[s2] = *(const u4*)(rb + ((((b2 * 8 + s2) ^ lane) & 63) << 4));
#pragma unroll
              for (int s2 = 0; s2 < 8; s2++)
                q1[s2] = *(const u4*)(rb + ((((32 + b2 * 8 + s2) ^ lane) & 63) << 4));
#pragma unroll
              for (int s2 = 0; s2 < 8; s2++) {
                const int e0 = b2 * 64 + s2 * 8;
                const f4 xa = *(const f4*)(h_l + e0), xb = *(const f4*)(h_l + e0 + 4);
                a0 = fmaf(LO16(q0[s2].x), xa.x, a0); a0 = fmaf(HI16(q0[s2].x), xa.y, a0);
                a0 = fmaf(LO16(q0[s2].y), xa.z, a0); a0 = fmaf(HI16(q0[s2].y), xa.w, a0);
                a0 = fmaf(LO16(q0[s2].z), xb.x, a0); a0 = fmaf(HI16(q0[s2].z), xb.y, a0);
                a0 = fmaf(LO16(q0[s2].w), xb.z, a0); a0 = fmaf(HI16(q0[s2].w), xb.w, a0);
                const int e1 = 256 + b2 * 64 + s2 * 8;
                const f4 ya = *(const f4*)(h_l + e1), yb = *(const f4*)(h_l + e1 + 4);
                a1 = fmaf(LO16(q1[s2].x), ya.x, a1); a1 = fmaf(HI16(q1[s2].x), ya.y, a1);
                a1 = fmaf(LO16(q1[s2].y), ya.z, a1); a1 = fmaf(HI16(q1[s2].y), ya.w, a1);
                a1 = fmaf(LO16(q1[s2].z), yb.x, a1); a1 = fmaf(HI16(q1[s2].z), yb.y, a1);
                a1 = fmaf(LO16(q1[s2].w), yb.z, a1); a1 = fmaf(HI16(q1[s2].w), yb.w, a1);
              }
            }
            const int bi = tt * 64 + lane;
            pa[bi * 2] = a0; pa[bi * 2 + 1] = a1;
          }
          __builtin_amdgcn_s_barrier();
        }
        __syncthreads();
      } else {
        if (tid < 384) {
          const int j = 128 + tid;
          float a0 = 0.f, a1 = 0.f;
          const f4* cw4 = (const f4*)catW + (size_t)j * 256;
          for (int b2 = 0; b2 < 8; b2++) {
            f4 q0[8], q1[8];
#pragma unroll
            for (int s2 = 0; s2 < 8; s2++) q0[s2] = cw4[b2 * 8 + s2];
#pragma unroll
            for (int s2 = 0; s2 < 8; s2++) q1[s2] = cw4[64 + b2 * 8 + s2];
#pragma unroll
            for (int s2 = 0; s2 < 8; s2++) {
              const int e0 = b2 * 32 + s2 * 4;
              const f4 xa = *(const f4*)(h_l + e0);
              a0 = fmaf(q0[s2].x, xa.x, a0); a0 = fmaf(q0[s2].y, xa.y, a0);
              a0 = fmaf(q0[s2].z, xa.z, a0); a0 = fmaf(q0[s2].w, xa.w, a0);
              const int e1 = 256 + b2 * 32 + s2 * 4;
              const f4 ya = *(const f4*)(h_l + e1);
              a1 = fmaf(q1[s2].x, ya.x, a1); a1 = fmaf(q1[s2].y, ya.y, a1);
              a1 = fmaf(q1[s2].z, ya.z, a1); a1 = fmaf(q1[s2].w, ya.w, a1);
            }
          }
          pa[tid * 2] = a0; pa[tid * 2 + 1] = a1;
        }
        __syncthreads();
      }
      // wait for cu, read it, finish rows with verbatim M2 chains
      if (tid == 0) fpoll(FLG + 2 * 8, (u32)(t + 1));
      __syncthreads();
      if (tid < 128) cuv[tid] = CUX[tid];
      __syncthreads();
      if (tid < 384) {
        const int j = 128 + tid;
        float a0 = pa[tid * 2], a1 = pa[tid * 2 + 1];
        const f4* m2 = (const f4*)(M2 + (size_t)j * 128);
#pragma unroll
        for (int b2 = 0; b2 < 2; b2++) {
          f4 q0[8], q1[8];
#pragma unroll
          for (int s2 = 0; s2 < 8; s2++) q0[s2] = m2[b2 * 8 + s2];
#pragma unroll
          for (int s2 = 0; s2 < 8; s2++) q1[s2] = m2[16 + b2 * 8 + s2];
#pragma unroll
          for (int s2 = 0; s2 < 8; s2++) {
            const int e0 = b2 * 32 + s2 * 4;
            const f4 xc = *(const f4*)(cuv + e0);
            a0 = fmaf(q0[s2].x, xc.x, a0); a0 = fmaf(q0[s2].y, xc.y, a0);
            a0 = fmaf(q0[s2].z, xc.z, a0); a0 = fmaf(q0[s2].w, xc.w, a0);
            const int e1 = 64 + b2 * 32 + s2 * 4;
            const f4 yc = *(const f4*)(cuv + e1);
            a1 = fmaf(q1[s2].x, yc.x, a1); a1 = fmaf(q1[s2].y, yc.y, a1);
            a1 = fmaf(q1[s2].z, yc.z, a1); a1 = fmaf(q1[s2].w, yc.w, a1);
          }
        }
        CCX[j] = tanhf(a0 + a1 + cbF[j]);   // plain store
      }
      __syncthreads();                      // vmcnt drain
      if (tid == 0) arrive(FLG + 3 * 8);    // kind3: ccB ready
      if (tid == 0) {                       // wait token from A
        fpoll(FLG + 4 * 8, (u32)(t + 1));
        s_tok = TKX[0];
      }
      __syncthreads();
    }
  }
}

extern "C" void kernel_launch(void* const* d_in, const int* in_sizes, int n_in,
                              void* d_out, int out_size, void* d_ws, size_t ws_size,
                              hipStream_t stream) {
  (void)in_sizes; (void)n_in; (void)out_size;
  if (ws_size < (size_t)W_END * 4) return;  // needs ~1.36 MB scratch
  hipLaunchKernelGGL(rnn_v11, dim3(NB), dim3(NT), 0, stream,
                     d_in[0],   // latent
                     d_in[1],   // upsampled_latent
                     d_in[3],   // embed (d_in[2]=target unused in eval)
                     d_in[4],   // hid_W
                     d_in[5],   // hid_b
                     d_in[6],   // mem_W
                     d_in[7],   // mem_b
                     d_in[8],   // W_ih
                     d_in[9],   // W_hh
                     d_in[10],  // b_ih
                     d_in[11],  // b_hh
                     d_in[12],  // cat_W
                     d_in[13],  // cat_b
                     d_in[14],  // out_W
                     d_in[15],  // out_b
                     d_out, (u32*)d_ws);
}

// Round 10
// 53832.153 us; speedup vs baseline: 1.8813x; 1.1629x over previous
//
#include <hip/hip_runtime.h>
#include <hip/hip_bf16.h>
#include <math.h>

// ============================================================================
// RNNDecoder v12: v11 (2 blocks/row, j-split GRU+cc, A=attention/logits,
// B=overlapped cc) with the cross-block exchange converted to a FULLY-RELAXED
// protocol: data via relaxed agent-scope atomic stores/loads (L2-bypass at
// the coherence point -> NO buffer_inv/wbl2 anywhere in the loop), flags via
// relaxed RMW after __syncthreads' vmcnt(0) drain. v11's acquire edges were
// invalidating each XCD's L2 2-3x/step (53 MB/step refetch). All compute
// chains byte-identical to v11 (= verbatim v4-v9; same argmax trajectory).
// ============================================================================

typedef unsigned short u16;
typedef unsigned int u32;
typedef float f4 __attribute__((ext_vector_type(4)));
typedef u32 u4 __attribute__((ext_vector_type(4)));

#define NB 256
#define NT 512
#define Ln 500
#define Hn 512
#define LDn 256
#define UDn 128
#define Vn 33
#define Tn 500
#define SENT_V 0x9E3779B1u

// ---- workspace u32 offsets (128 pairs) ----
#define W_INITC 0u
#define W_SENT  1u
#define W_FLG   64u        // [128 pair][8 kind][8 pad]; 0=hA 1=hB 2=cu 3=ccB 4=tok
#define W_HX    8256u      // f32 [128][512] h exchange
#define W_CUX   73792u     // f32 [128][128]
#define W_CCX   90176u     // f32 [128][512] (B writes [128,512))
#define W_TOKX  155712u    // int [128][8]
#define W_GEM   156736u    // f32 [33][1536]
#define W_M2    207424u    // f32 [512][128]
#define W_CB    272960u    // f32 [512]
#define W_MWT   273472u    // f32 [128][512] memW^T
#define W_END   339008u    // ~1.36 MB

__device__ __forceinline__ float b2f(u16 v) {
  u32 x = ((u32)v) << 16; float f; __builtin_memcpy(&f, &x, 4); return f;
}
__device__ __forceinline__ float bitsf(u32 x) {
  float f; __builtin_memcpy(&f, &x, 4); return f;
}
#define LO16(d) bitsf((u32)(d) << 16)
#define HI16(d) bitsf((u32)(d) & 0xffff0000u)
__device__ __forceinline__ u16 f2b(float f) {  // RNE
  u32 x; __builtin_memcpy(&x, &f, 4);
  x += 0x7fffu + ((x >> 16) & 1u);
  return (u16)(x >> 16);
}
__device__ __forceinline__ float ldv(const void* p, size_t i, int mode) {
  return mode ? b2f(((const u16*)p)[i]) : ((const float*)p)[i];
}
__device__ __forceinline__ u32 aload(u32* p) {
  return __hip_atomic_load(p, __ATOMIC_ACQUIRE, __HIP_MEMORY_SCOPE_AGENT);
}
__device__ __forceinline__ void waitGe(u32* p, u32 tgt) {
  while (aload(p) < tgt) __builtin_amdgcn_s_sleep(4);
}
__device__ __forceinline__ void astore(u32* p, u32 v) {
  __hip_atomic_store(p, v, __ATOMIC_RELEASE, __HIP_MEMORY_SCOPE_AGENT);
}
// ---- fully-relaxed exchange primitives (no L2 cache maintenance) ----
__device__ __forceinline__ void rarrive(u32* p) {  // relaxed RMW @ coherence pt
  __hip_atomic_fetch_add(p, 1u, __ATOMIC_RELAXED, __HIP_MEMORY_SCOPE_AGENT);
}
__device__ __forceinline__ void pace_zero(u32* p) {
  __hip_atomic_store(p, 0u, __ATOMIC_RELAXED, __HIP_MEMORY_SCOPE_AGENT);
}
__device__ __forceinline__ void rpoll(u32* p, u32 tgt) {  // relaxed-only poll
  while (__hip_atomic_load(p, __ATOMIC_RELAXED, __HIP_MEMORY_SCOPE_AGENT) < tgt)
    __builtin_amdgcn_s_sleep(2);
}
__device__ __forceinline__ void rstoref(float* p, float v) {
  u32 x; __builtin_memcpy(&x, &v, 4);
  __hip_atomic_store((u32*)p, x, __ATOMIC_RELAXED, __HIP_MEMORY_SCOPE_AGENT);
}
__device__ __forceinline__ float rloadf(const float* p) {
  u32 x = __hip_atomic_load((const u32*)p, __ATOMIC_RELAXED, __HIP_MEMORY_SCOPE_AGENT);
  float f; __builtin_memcpy(&f, &x, 4); return f;
}
__device__ __forceinline__ void rstorei(int* p, int v) {
  __hip_atomic_store((u32*)p, (u32)v, __ATOMIC_RELAXED, __HIP_MEMORY_SCOPE_AGENT);
}
__device__ __forceinline__ int rloadi(const int* p) {
  return (int)__hip_atomic_load((const u32*)p, __ATOMIC_RELAXED, __HIP_MEMORY_SCOPE_AGENT);
}
__device__ __forceinline__ void stage16(const void* g, void* l) {
  __builtin_amdgcn_global_load_lds(
      (const __attribute__((address_space(1))) u32*)g,
      (__attribute__((address_space(3))) u32*)l, 16, 0, 0);
}

extern "C" __global__ void __launch_bounds__(512, 2)
rnn_v12(const void* latent, const void* ulat, const void* embd,
        const void* hidW, const void* hidb, const void* memW, const void* memb,
        const void* Wih, const void* Whh, const void* bih, const void* bhh,
        const void* catW, const void* catb, const void* outW, const void* outb,
        void* out, u32* ws) {
  __shared__ __align__(16) char  stage[131072];
  __shared__ __align__(16) char  arena[12288];
  __shared__ __align__(16) float bhh_l[1536];
  __shared__ __align__(16) float h_l[Hn];
  __shared__ float misc_l[2];
  __shared__ int   s_tok;
  __shared__ u32   s_det;

  const int tid = threadIdx.x, blk = blockIdx.x;
  const int wv = tid >> 6, lane = tid & 63;
  const int pr = blk >> 1, role = blk & 1;   // pair row (0..127), A=0/B=1
  const int gtid = blk * NT + tid;

  if (tid == 0) s_det = 0u;
  __syncthreads();
  if (tid < 256) {
    u32 v = ((const u32*)embd)[256 + tid];
    if (v) atomicOr(&s_det, 1u);
  }
  __syncthreads();
  const int mode = (s_det == 0u) ? 1 : 0;

  float* GEM = (float*)(ws + W_GEM);
  float* M2  = (float*)(ws + W_M2);
  float* cbF = (float*)(ws + W_CB);
  float* mWT = (float*)(ws + W_MWT);
  float* HX  = (float*)(ws + W_HX) + (size_t)pr * 512;
  float* CUX = (float*)(ws + W_CUX) + (size_t)pr * 128;
  float* CCX = (float*)(ws + W_CCX) + (size_t)pr * 512;
  int*   TKX = (int*)(ws + W_TOKX) + (size_t)pr * 8;
  u32*   FLG = ws + W_FLG + (u32)pr * 64u;   // + kind*8

  float* ghq   = (float*)arena;            // GRU: [768] local rows
  float* pa    = (float*)arena;            // B cc: [384][2] partials (post-gates)
  float* ps    = (float*)arena;            // A attn
  float* ss    = (float*)(arena + 512);
  float* es    = (float*)(arena + 2560);
  float* Bpart = (float*)(arena + 4608);
  float* cuv   = (float*)(arena + 8704);
  float* ccs   = (float*)(arena + 4608);   // A: [512] cc gather
  float* lgs   = (float*)(arena + 6656);

  // ======================= per-block init ===================================
  for (int i = tid; i < 1536; i += NT) bhh_l[i] = ldv(bhh, i, mode);
  {  // full h0 (verbatim chain), computed redundantly by both pair members
    int k = tid;
    float a = ldv(hidb, k, mode);
    for (int q = 0; q < LDn; q++)
      a += ldv(latent, (size_t)pr * LDn + q, mode) * ldv(hidW, (size_t)k * LDn + q, mode);
    h_l[k] = a;
  }
  if (tid == 0) s_tok = 0;

  // ======================= cooperative ws build =============================
  if (gtid < 8192) pace_zero(ws + W_FLG + gtid);       // flags zero (128 pairs)
  if (gtid < 50688) {
    int v = gtid / 1536, j = gtid - v * 1536;
    float a = ldv(bih, j, mode);
    for (int k = 0; k < Hn; k++)
      a += ldv(embd, (size_t)v * Hn + k, mode) * ldv(Wih, (size_t)j * Hn + k, mode);
    GEM[gtid] = a;
  }
  if (gtid < 65536) {
    int j = gtid >> 7, u = gtid & 127;
    float a = 0.f;
    for (int h = 0; h < Hn; h++)
      a += ldv(catW, (size_t)j * 1024 + 512 + h, mode) * ldv(memW, (size_t)h * UDn + u, mode);
    M2[(size_t)j * 128 + u] = a;
  }
  if (gtid < 65536) {
    int u = gtid >> 9, k = gtid & 511;
    mWT[(size_t)u * 512 + k] = ldv(memW, (size_t)k * UDn + u, mode);
  }
  if (gtid < 512) {
    int j = gtid;
    float a = ldv(catb, j, mode);
    for (int h = 0; h < Hn; h++)
      a += ldv(catW, (size_t)j * 1024 + 512 + h, mode) * ldv(memb, h, mode);
    cbF[j] = a;
  }
  __threadfence();
  __syncthreads();
  if (tid == 0) {  // poison-agnostic device barrier (one-time acq/rel is fine)
    if (blk == 0) {
      __hip_atomic_store(ws + W_INITC, 0u, __ATOMIC_RELAXED, __HIP_MEMORY_SCOPE_AGENT);
      astore(ws + W_SENT, SENT_V);
    }
    while (aload(ws + W_SENT) != SENT_V) __builtin_amdgcn_s_sleep(8);
    __hip_atomic_fetch_add(ws + W_INITC, 1u, __ATOMIC_ACQ_REL, __HIP_MEMORY_SCOPE_AGENT);
    waitGe(ws + W_INITC, NB);
  }
  __syncthreads();

  const int roff = role * 256;  // this block's j-offset

  // ======================= 500 decode steps =================================
  for (int t = 0; t < Tn; t++) {
    __syncthreads();

    // ---- GRU: 768 rows (this half), v9 ring pipeline, chains verbatim -----
    {
      const int c = lane & 7;
      f4 xv[16];
#pragma unroll
      for (int i = 0; i < 16; i++) xv[i] = *(const f4*)(h_l + c * 64 + i * 4);
      const int base = lane & 56;
      if (mode) {
        const u32 soff = (u32)((lane >> 3) * 128 + (((lane & 7) ^ (lane >> 3)) * 16));
        const char* W = (const char*)Whh;
        const int rp = lane >> 3;
#pragma unroll
        for (int r = 0; r < 8; r++) {
          const int ri = wv * 8 + r;
          const int wrow = (ri >> 8) * 512 + roff + (ri & 255);
          stage16(W + (size_t)wrow * 1024 + soff, stage + (size_t)ri * 1024);
        }
        for (int tt = 0; tt < 12; tt++) {
          if (tt < 11) {
            char* nbuf = stage + (size_t)((tt + 1) & 1) * 65536;
#pragma unroll
            for (int r = 0; r < 8; r++) {
              const int rl = wv * 8 + r, ri = (tt + 1) * 64 + rl;
              const int wrow = (ri >> 8) * 512 + roff + (ri & 255);
              stage16(W + (size_t)wrow * 1024 + soff, nbuf + (size_t)rl * 1024);
            }
            asm volatile("s_waitcnt vmcnt(8)" ::: "memory");
          } else {
            asm volatile("s_waitcnt vmcnt(0)" ::: "memory");
          }
          const char* rb = stage + (size_t)(tt & 1) * 65536 +
                           (size_t)(wv * 8 + rp) * 1024 + c * 128;
          float a = 0.f;
#pragma unroll
          for (int s = 0; s < 8; s++) {
            const u4 q = *(const u4*)(rb + ((s ^ c) * 16));
            const f4 xa = xv[s * 2], xb = xv[s * 2 + 1];
            a = fmaf(LO16(q.x), xa.x, fmaf(HI16(q.x), xa.y,
                fmaf(LO16(q.y), xa.z, fmaf(HI16(q.y), xa.w, a))));
            a = fmaf(LO16(q.z), xb.x, fmaf(HI16(q.z), xb.y,
                fmaf(LO16(q.w), xb.z, fmaf(HI16(q.w), xb.w, a))));
          }
          float sf = __shfl(a, base);
#pragma unroll
          for (int c2 = 1; c2 < 8; c2++) sf += __shfl(a, base + c2);
          if (c == 0) {
            const int ri = tt * 64 + wv * 8 + rp;
            const int wrow = (ri >> 8) * 512 + roff + (ri & 255);
            ghq[ri] = sf + bhh_l[wrow];
          }
        }
      } else {
        const u32 l4 = (u32)(lane & 15);
        const u32 cs0 = (u32)(lane >> 4), cs1 = cs0 + 4;
        const u32 soff0 = cs0 * 256 + (((l4 & 8) | ((l4 ^ cs0) & 7))) * 16;
        const u32 soff1 = cs1 * 256 + (((l4 & 8) | ((l4 ^ cs1) & 7))) * 16;
        const char* W = (const char*)Whh;
        const int rp = lane >> 3, act = (lane < 32);
#pragma unroll
        for (int r = 0; r < 4; r++) {
          const int ri = wv * 4 + r;
          const int wrow = (ri >> 8) * 512 + roff + (ri & 255);
          const char* src = W + (size_t)wrow * 2048;
          char* dst = stage + (size_t)ri * 2048;
          stage16(src + soff0, dst);
          stage16(src + soff1, dst + 1024);
        }
        for (int tt = 0; tt < 24; tt++) {
          if (tt < 23) {
            char* nbuf = stage + (size_t)((tt + 1) & 1) * 65536;
#pragma unroll
            for (int r = 0; r < 4; r++) {
              const int rl = wv * 4 + r, ri = (tt + 1) * 32 + rl;
              const int wrow = (ri >> 8) * 512 + roff + (ri & 255);
              const char* src = W + (size_t)wrow * 2048;
              char* dst = nbuf + (size_t)rl * 2048;
              stage16(src + soff0, dst);
              stage16(src + soff1, dst + 1024);
            }
            asm volatile("s_waitcnt vmcnt(8)" ::: "memory");
          } else {
            asm volatile("s_waitcnt vmcnt(0)" ::: "memory");
          }
          if (act) {
            const char* rb = stage + (size_t)(tt & 1) * 65536 +
                             (size_t)(wv * 4 + rp) * 2048 + c * 256;
            float a = 0.f;
#pragma unroll
            for (int i = 0; i < 16; i++) {
              const u32 j = (u32)((i & 8) | ((i ^ c) & 7));
              const f4 q = *(const f4*)(rb + j * 16);
              const f4 x = xv[i];
              a = fmaf(q.x, x.x, fmaf(q.y, x.y, fmaf(q.z, x.z, fmaf(q.w, x.w, a))));
            }
            float sf = __shfl(a, base);
#pragma unroll
            for (int c2 = 1; c2 < 8; c2++) sf += __shfl(a, base + c2);
            if (c == 0) {
              const int ri = tt * 32 + wv * 4 + rp;
              const int wrow = (ri >> 8) * 512 + roff + (ri & 255);
              ghq[ri] = sf + bhh_l[wrow];
            }
          }
        }
      }
    }
    __syncthreads();

    // ---- gates (256 own rows; verbatim formulas) + publish h half ---------
    if (tid < 256) {
      const int jl = tid, jg = roff + jl;
      int tk = s_tok;
      if ((unsigned)tk > 32u) tk = 0;
      const float giR = GEM[tk * 1536 + jg];
      const float giZ = GEM[tk * 1536 + 512 + jg];
      const float giN = GEM[tk * 1536 + 1024 + jg];
      const float rr = 1.f / (1.f + expf(-(giR + ghq[jl])));
      const float zz = 1.f / (1.f + expf(-(giZ + ghq[256 + jl])));
      const float nn = tanhf(giN + rr * ghq[512 + jl]);
      const float hv = h_l[jg];
      const float hnew = (1.f - zz) * nn + zz * hv;
      h_l[jg] = hnew;
      rstoref(&HX[jg], hnew);             // relaxed atomic store (coherence pt)
    }
    __syncthreads();                      // drains vmcnt for all waves
    if (tid == 0) rarrive(FLG + role * 8);       // kind 0/1: my h half ready
    if (tid == 0) rpoll(FLG + (1 - role) * 8, (u32)(t + 1));
    __syncthreads();
    if (tid < 256) {                      // read partner's h half (relaxed)
      const int jo = (1 - role) * 256 + tid;
      h_l[jo] = rloadf(&HX[jo]);
    }
    __syncthreads();

    if (role == 0) {
      // =========== A: attention (verbatim v9) → publish cu ================
      {
        const int u = tid & 127, c8 = tid >> 7;
        const f4* mw = (const f4*)(mWT + (size_t)u * 512);
        float aa = 0.f, ab = 0.f;
#pragma unroll
        for (int b = 0; b < 2; b++) {
          f4 qa[8], qb[8];
#pragma unroll
          for (int s = 0; s < 8; s++) qa[s] = mw[c8 * 16 + b * 8 + s];
#pragma unroll
          for (int s = 0; s < 8; s++) qb[s] = mw[(c8 + 4) * 16 + b * 8 + s];
#pragma unroll
          for (int s = 0; s < 8; s++) {
            const int k0 = c8 * 64 + b * 32 + s * 4;
            const f4 xa = *(const f4*)(h_l + k0);
            aa = fmaf(qa[s].x, xa.x, aa); aa = fmaf(qa[s].y, xa.y, aa);
            aa = fmaf(qa[s].z, xa.z, aa); aa = fmaf(qa[s].w, xa.w, aa);
            const int k1 = (c8 + 4) * 64 + b * 32 + s * 4;
            const f4 xb = *(const f4*)(h_l + k1);
            ab = fmaf(qb[s].x, xb.x, ab); ab = fmaf(qb[s].y, xb.y, ab);
            ab = fmaf(qb[s].z, xb.z, ab); ab = fmaf(qb[s].w, xb.w, ab);
          }
        }
        Bpart[c8 * UDn + u] = aa;
        Bpart[(c8 + 4) * UDn + u] = ab;
      }
      __syncthreads();
      if (tid < 128) {
        float s = 0.f;
#pragma unroll
        for (int c = 0; c < 8; c++) s += Bpart[c * UDn + tid];
        ps[tid] = s;
      } else if (tid < 192) {
        const int ln = tid - 128;
        float a = 0.f;
#pragma unroll
        for (int i = 0; i < 8; i++) { int k = ln + i * 64; a = fmaf(h_l[k], ldv(memb, k, mode), a); }
        for (int o = 32; o; o >>= 1) a += __shfl_down(a, o);
        if (ln == 0) misc_l[0] = a;
      }
      __syncthreads();
#pragma unroll
      for (int rep = 0; rep < 2; rep++) {
        const int l = (wv << 5) + (lane >> 1) + rep * 256, uh = lane & 1;
        float val = 0.f;
        if (l < Ln) {
          if (mode) {
            const u4* q4 = (const u4*)((const u32*)ulat +
                                       ((size_t)pr * Ln + l) * 64 + uh * 32);
            u4 Q[8];
#pragma unroll
            for (int s = 0; s < 8; s++) Q[s] = q4[s];
#pragma unroll
            for (int s = 0; s < 8; s++) {
#pragma unroll
              for (int e = 0; e < 4; e++) {
                const u32 d = Q[s][e];
                const int i = s * 4 + e;
                val = fmaf(bitsf(d << 16), ps[uh * 64 + i * 2], val);
                val = fmaf(bitsf(d & 0xffff0000u), ps[uh * 64 + i * 2 + 1], val);
              }
            }
          } else {
            const float* q = (const float*)ulat + ((size_t)pr * Ln + l) * UDn + uh * 64;
#pragma unroll 8
            for (int i = 0; i < 64; i++) val = fmaf(q[i], ps[uh * 64 + i], val);
          }
        }
        const float v2v = __shfl_down(val, 1);
        if ((lane & 1) == 0 && l < Ln) ss[l] = val + v2v + misc_l[0];
      }
      __syncthreads();
      if (wv == 0) {
        float mx = -3.4e38f;
        for (int i = 0; i < 8; i++) {
          int l = lane + (i << 6);
          if (l < Ln) mx = fmaxf(mx, ss[l]);
        }
        for (int o = 32; o; o >>= 1) mx = fmaxf(mx, __shfl_xor(mx, o));
        float sum = 0.f;
        for (int i = 0; i < 8; i++) {
          int l = lane + (i << 6);
          if (l < Ln) { float e = expf(ss[l] - mx); es[l] = e; sum += e; }
        }
        for (int o = 32; o; o >>= 1) sum += __shfl_xor(sum, o);
        if (lane == 0) misc_l[1] = 1.f / sum;
      }
      __syncthreads();
      {
        const int u = tid & 127, lc = tid >> 7;
        float aa = 0.f, ab = 0.f;
        if (mode) {
          const u16* q = (const u16*)ulat + ((size_t)pr * Ln) * UDn + u;
          const int e0 = (lc * 64 + 64 < Ln) ? lc * 64 + 64 : Ln;
#pragma unroll 8
          for (int l = lc * 64; l < e0; l++) aa = fmaf(es[l], b2f(q[(size_t)l * UDn]), aa);
          const int e1 = ((lc + 4) * 64 + 64 < Ln) ? (lc + 4) * 64 + 64 : Ln;
#pragma unroll 8
          for (int l = (lc + 4) * 64; l < e1; l++) ab = fmaf(es[l], b2f(q[(size_t)l * UDn]), ab);
        } else {
          const float* q = (const float*)ulat + ((size_t)pr * Ln) * UDn + u;
          const int e0 = (lc * 64 + 64 < Ln) ? lc * 64 + 64 : Ln;
#pragma unroll 8
          for (int l = lc * 64; l < e0; l++) aa = fmaf(es[l], q[(size_t)l * UDn], aa);
          const int e1 = ((lc + 4) * 64 + 64 < Ln) ? (lc + 4) * 64 + 64 : Ln;
#pragma unroll 8
          for (int l = (lc + 4) * 64; l < e1; l++) ab = fmaf(es[l], q[(size_t)l * UDn], ab);
        }
        Bpart[lc * UDn + u] = aa;
        Bpart[(lc + 4) * UDn + u] = ab;
      }
      __syncthreads();
      if (tid < 128) {
        float s = 0.f;
#pragma unroll
        for (int c = 0; c < 8; c++) s += Bpart[c * UDn + tid];
        const float cv = s * misc_l[1];
        cuv[tid] = cv;
        rstoref(&CUX[tid], cv);           // relaxed atomic store
      }
      __syncthreads();                    // vmcnt drain
      if (tid == 0) rarrive(FLG + 2 * 8); // kind2: cu ready

      // ---- A's cc rows j in [0,128): v8 register chains (verbatim) --------
      if (tid < 128) {
        const int j = tid;
        float a0 = 0.f, a1 = 0.f;
        if (mode) {
          const u4* cw = (const u4*)((const u16*)catW + (size_t)j * 1024);
          for (int b2 = 0; b2 < 4; b2++) {
            u4 q0[8], q1[8];
#pragma unroll
            for (int s2 = 0; s2 < 8; s2++) q0[s2] = cw[b2 * 8 + s2];
#pragma unroll
            for (int s2 = 0; s2 < 8; s2++) q1[s2] = cw[32 + b2 * 8 + s2];
#pragma unroll
            for (int s2 = 0; s2 < 8; s2++) {
              const int e0 = b2 * 64 + s2 * 8;
              const f4 xa = *(const f4*)(h_l + e0), xb = *(const f4*)(h_l + e0 + 4);
              a0 = fmaf(LO16(q0[s2].x), xa.x, a0); a0 = fmaf(HI16(q0[s2].x), xa.y, a0);
              a0 = fmaf(LO16(q0[s2].y), xa.z, a0); a0 = fmaf(HI16(q0[s2].y), xa.w, a0);
              a0 = fmaf(LO16(q0[s2].z), xb.x, a0); a0 = fmaf(HI16(q0[s2].z), xb.y, a0);
              a0 = fmaf(LO16(q0[s2].w), xb.z, a0); a0 = fmaf(HI16(q0[s2].w), xb.w, a0);
              const int e1 = 256 + b2 * 64 + s2 * 8;
              const f4 ya = *(const f4*)(h_l + e1), yb = *(const f4*)(h_l + e1 + 4);
              a1 = fmaf(LO16(q1[s2].x), ya.x, a1); a1 = fmaf(HI16(q1[s2].x), ya.y, a1);
              a1 = fmaf(LO16(q1[s2].y), ya.z, a1); a1 = fmaf(HI16(q1[s2].y), ya.w, a1);
              a1 = fmaf(LO16(q1[s2].z), yb.x, a1); a1 = fmaf(HI16(q1[s2].z), yb.y, a1);
              a1 = fmaf(LO16(q1[s2].w), yb.z, a1); a1 = fmaf(HI16(q1[s2].w), yb.w, a1);
            }
          }
        } else {
          const f4* cw4 = (const f4*)catW + (size_t)j * 256;
          for (int b2 = 0; b2 < 8; b2++) {
            f4 q0[8], q1[8];
#pragma unroll
            for (int s2 = 0; s2 < 8; s2++) q0[s2] = cw4[b2 * 8 + s2];
#pragma unroll
            for (int s2 = 0; s2 < 8; s2++) q1[s2] = cw4[64 + b2 * 8 + s2];
#pragma unroll
            for (int s2 = 0; s2 < 8; s2++) {
              const int e0 = b2 * 32 + s2 * 4;
              const f4 xa = *(const f4*)(h_l + e0);
              a0 = fmaf(q0[s2].x, xa.x, a0); a0 = fmaf(q0[s2].y, xa.y, a0);
              a0 = fmaf(q0[s2].z, xa.z, a0); a0 = fmaf(q0[s2].w, xa.w, a0);
              const int e1 = 256 + b2 * 32 + s2 * 4;
              const f4 ya = *(const f4*)(h_l + e1);
              a1 = fmaf(q1[s2].x, ya.x, a1); a1 = fmaf(q1[s2].y, ya.y, a1);
              a1 = fmaf(q1[s2].z, ya.z, a1); a1 = fmaf(q1[s2].w, ya.w, a1);
            }
          }
        }
        {
          const f4* m2 = (const f4*)(M2 + (size_t)j * 128);
#pragma unroll
          for (int b2 = 0; b2 < 2; b2++) {
            f4 q0[8], q1[8];
#pragma unroll
            for (int s2 = 0; s2 < 8; s2++) q0[s2] = m2[b2 * 8 + s2];
#pragma unroll
            for (int s2 = 0; s2 < 8; s2++) q1[s2] = m2[16 + b2 * 8 + s2];
#pragma unroll
            for (int s2 = 0; s2 < 8; s2++) {
              const int e0 = b2 * 32 + s2 * 4;
              const f4 xc = *(const f4*)(cuv + e0);
              a0 = fmaf(q0[s2].x, xc.x, a0); a0 = fmaf(q0[s2].y, xc.y, a0);
              a0 = fmaf(q0[s2].z, xc.z, a0); a0 = fmaf(q0[s2].w, xc.w, a0);
              const int e1 = 64 + b2 * 32 + s2 * 4;
              const f4 yc = *(const f4*)(cuv + e1);
              a1 = fmaf(q1[s2].x, yc.x, a1); a1 = fmaf(q1[s2].y, yc.y, a1);
              a1 = fmaf(q1[s2].z, yc.z, a1); a1 = fmaf(q1[s2].w, yc.w, a1);
            }
          }
        }
        ccs[j] = tanhf(a0 + a1 + cbF[j]);
      }
      if (tid == 0) rpoll(FLG + 3 * 8, (u32)(t + 1));  // ccB ready
      __syncthreads();
      if (tid >= 128) ccs[tid] = rloadf(&CCX[tid]);  // gather B's cc (relaxed)
      __syncthreads();

      // ---- logits + argmax + output (verbatim) ----------------------------
#pragma unroll
      for (int rep = 0; rep < 2; rep++) {
        if (lane < Vn) {
          const int w2i = wv + rep * 8;
          const int j0 = w2i << 5;
          float part = 0.f;
#pragma unroll
          for (int q = 0; q < 32; q++)
            part = fmaf(ccs[j0 + q], ldv(outW, (size_t)lane * Hn + j0 + q, mode), part);
          lgs[w2i * 34 + lane] = part;
        }
      }
      __syncthreads();
      if (wv == 0) {
        float lg = -3.4e38f;
        int idx = 0;
        if (lane < Vn) {
          float s = ldv(outb, lane, mode);
#pragma unroll
          for (int w2 = 0; w2 < 16; w2++) s += lgs[w2 * 34 + lane];
          if (mode) ((u16*)out)[(size_t)pr * (Vn * Ln) + lane * Ln + t] = f2b(s);
          else ((float*)out)[(size_t)pr * (Vn * Ln) + lane * Ln + t] = s;
          lg = s;
          idx = lane;
        }
        for (int o = 32; o; o >>= 1) {
          const float ov = __shfl_down(lg, o);
          const int oi = __shfl_down(idx, o);
          if (ov > lg || (ov == lg && oi < idx)) { lg = ov; idx = oi; }
        }
        if (lane == 0) { s_tok = idx; rstorei(&TKX[0], idx); }
        asm volatile("s_waitcnt vmcnt(0)" ::: "memory");
        if (lane == 0) rarrive(FLG + 4 * 8);  // kind4: token ready
      }
    } else {
      // =========== B: cc catW-part (h-only) overlapped, then finish =======
      if (mode) {
        const char* CW = (const char*)catW;
#pragma unroll
        for (int r = 0; r < 8; r++) {
          const int rl = wv * 8 + r, row = 128 + rl;
          const u32 so = (u32)(((lane ^ row) & 63) << 4);
          stage16(CW + (size_t)row * 2048 + so, stage + (size_t)rl * 1024);
        }
        for (int tt = 0; tt < 6; tt++) {
          if (tt < 5) {
            char* nbuf = stage + (size_t)((tt + 1) & 1) * 65536;
#pragma unroll
            for (int r = 0; r < 8; r++) {
              const int rl = wv * 8 + r, row = 128 + (tt + 1) * 64 + rl;
              const u32 so = (u32)(((lane ^ row) & 63) << 4);
              stage16(CW + (size_t)row * 2048 + so, nbuf + (size_t)rl * 1024);
            }
            asm volatile("s_waitcnt vmcnt(8)" ::: "memory");
          } else {
            asm volatile("s_waitcnt vmcnt(0)" ::: "memory");
          }
          __builtin_amdgcn_sched_barrier(0);
          __builtin_amdgcn_s_barrier();
          if (wv == tt) {
            const char* rb = stage + (size_t)(tt & 1) * 65536 + (size_t)lane * 1024;
            float a0 = 0.f, a1 = 0.f;
            for (int b2 = 0; b2 < 4; b2++) {
              u4 q0[8], q1[8];
#pragma unroll
              for (int s2 = 0; s2 < 8; s2++)
                q0[s2] = *(const u4*)(rb + ((((b2 * 8 + s2) ^ lane) & 63) << 4));
#pragma unroll
              for (int s2 = 0; s2 < 8; s2++)
                q1[s2] = *(const u4*)(rb + ((((32 + b2 * 8 + s2) ^ lane) & 63) << 4));
#pragma unroll
              for (int s2 = 0; s2 < 8; s2++) {
                const int e0 = b2 * 64 + s2 * 8;
                const f4 xa = *(const f4*)(h_l + e0), xb = *(const f4*)(h_l + e0 + 4);
                a0 = fmaf(LO16(q0[s2].x), xa.x, a0); a0 = fmaf(HI16(q0[s2].x), xa.y, a0);
                a0 = fmaf(LO16(q0[s2].y), xa.z, a0); a0 = fmaf(HI16(q0[s2].y), xa.w, a0);
                a0 = fmaf(LO16(q0[s2].z), xb.x, a0); a0 = fmaf(HI16(q0[s2].z), xb.y, a0);
                a0 = fmaf(LO16(q0[s2].w), xb.z, a0); a0 = fmaf(HI16(q0[s2].w), xb.w, a0);
                const int e1 = 256 + b2 * 64 + s2 * 8;
                const f4 ya = *(const f4*)(h_l + e1), yb = *(const f4*)(h_l + e1 + 4);
                a1 = fmaf(LO16(q1[s2].x), ya.x, a1); a1 = fmaf(HI16(q1[s2].x), ya.y, a1);
                a1 = fmaf(LO16(q1[s2].y), ya.z, a1); a1 = fmaf(HI16(q1[s2].y), ya.w, a1);
                a1 = fmaf(LO16(q1[s2].z), yb.x, a1); a1 = fmaf(HI16(q1[s2].z), yb.y, a1);
                a1 = fmaf(LO16(q1[s2].w), yb.z, a1); a1 = fmaf(HI16(q1[s2].w), yb.w, a1);
              }
            }
            const int bi = tt * 64 + lane;
            pa[bi * 2] = a0; pa[bi * 2 + 1] = a1;
          }
          __builtin_amdgcn_s_barrier();
        }
        __syncthreads();
      } else {
        if (tid < 384) {
          const int j = 128 + tid;
          float a0 = 0.f, a1 = 0.f;
          const f4* cw4 = (const f4*)catW + (size_t)j * 256;
          for (int b2 = 0; b2 < 8; b2++) {
            f4 q0[8], q1[8];
#pragma unroll
            for (int s2 = 0; s2 < 8; s2++) q0[s2] = cw4[b2 * 8 + s2];
#pragma unroll
            for (int s2 = 0; s2 < 8; s2++) q1[s2] = cw4[64 + b2 * 8 + s2];
#pragma unroll
            for (int s2 = 0; s2 < 8; s2++) {
              const int e0 = b2 * 32 + s2 * 4;
              const f4 xa = *(const f4*)(h_l + e0);
              a0 = fmaf(q0[s2].x, xa.x, a0); a0 = fmaf(q0[s2].y, xa.y, a0);
              a0 = fmaf(q0[s2].z, xa.z, a0); a0 = fmaf(q0[s2].w, xa.w, a0);
              const int e1 = 256 + b2 * 32 + s2 * 4;
              const f4 ya = *(const f4*)(h_l + e1);
              a1 = fmaf(q1[s2].x, ya.x, a1); a1 = fmaf(q1[s2].y, ya.y, a1);
              a1 = fmaf(q1[s2].z, ya.z, a1); a1 = fmaf(q1[s2].w, ya.w, a1);
            }
          }
          pa[tid * 2] = a0; pa[tid * 2 + 1] = a1;
        }
        __syncthreads();
      }
      // wait for cu, read it (relaxed), finish rows with verbatim M2 chains
      if (tid == 0) rpoll(FLG + 2 * 8, (u32)(t + 1));
      __syncthreads();
      if (tid < 128) cuv[tid] = rloadf(&CUX[tid]);
      __syncthreads();
      if (tid < 384) {
        const int j = 128 + tid;
        float a0 = pa[tid * 2], a1 = pa[tid * 2 + 1];
        const f4* m2 = (const f4*)(M2 + (size_t)j * 128);
#pragma unroll
        for (int b2 = 0; b2 < 2; b2++) {
          f4 q0[8], q1[8];
#pragma unroll
          for (int s2 = 0; s2 < 8; s2++) q0[s2] = m2[b2 * 8 + s2];
#pragma unroll
          for (int s2 = 0; s2 < 8; s2++) q1[s2] = m2[16 + b2 * 8 + s2];
#pragma unroll
          for (int s2 = 0; s2 < 8; s2++) {
            const int e0 = b2 * 32 + s2 * 4;
            const f4 xc = *(const f4*)(cuv + e0);
            a0 = fmaf(q0[s2].x, xc.x, a0); a0 = fmaf(q0[s2].y, xc.y, a0);
            a0 = fmaf(q0[s2].z, xc.z, a0); a0 = fmaf(q0[s2].w, xc.w, a0);
            const int e1 = 64 + b2 * 32 + s2 * 4;
            const f4 yc = *(const f4*)(cuv + e1);
            a1 = fmaf(q1[s2].x, yc.x, a1); a1 = fmaf(q1[s2].y, yc.y, a1);
            a1 = fmaf(q1[s2].z, yc.z, a1); a1 = fmaf(q1[s2].w, yc.w, a1);
          }
        }
        rstoref(&CCX[j], tanhf(a0 + a1 + cbF[j]));  // relaxed atomic store
      }
      __syncthreads();                      // vmcnt drain
      if (tid == 0) rarrive(FLG + 3 * 8);   // kind3: ccB ready
      if (tid == 0) {                       // wait token from A (relaxed)
        rpoll(FLG + 4 * 8, (u32)(t + 1));
        s_tok = rloadi(&TKX[0]);
      }
      __syncthreads();
    }
  }
}

extern "C" void kernel_launch(void* const* d_in, const int* in_sizes, int n_in,
                              void* d_out, int out_size, void* d_ws, size_t ws_size,
                              hipStream_t stream) {
  (void)in_sizes; (void)n_in; (void)out_size;
  if (ws_size < (size_t)W_END * 4) return;  // needs ~1.36 MB scratch
  hipLaunchKernelGGL(rnn_v12, dim3(NB), dim3(NT), 0, stream,
                     d_in[0],   // latent
                     d_in[1],   // upsampled_latent
                     d_in[3],   // embed (d_in[2]=target unused in eval)
                     d_in[4],   // hid_W
                     d_in[5],   // hid_b
                     d_in[6],   // mem_W
                     d_in[7],   // mem_b
                     d_in[8],   // W_ih
                     d_in[9],   // W_hh
                     d_in[10],  // b_ih
                     d_in[11],  // b_hh
                     d_in[12],  // cat_W
                     d_in[13],  // cat_b
                     d_in[14],  // out_W
                     d_in[15],  // out_b
                     d_out, (u32*)d_ws);
}